// Round 1
// baseline (721.612 us; speedup 1.0000x reference)
//
#include <hip/hip_runtime.h>

// PointNet2 FP module: 3-NN interpolate + concat + MLP(384->256->128, ReLU)
// B=2, N=16384, M=4096, C1=128 (unknow_feats), C2=256 (known_feats)
#define BB 2
#define NN 16384
#define MM 4096
#define C1 128
#define C2 256
#define CIN 384   // C1+C2
#define H1 256
#define H2 128
#define TILE 16

// ---------------- Kernel A: 3-NN + inverse-distance weights ----------------
// grid: (NN/128, BB), block: 256. Two threads per query, each scans half of M.
__global__ __launch_bounds__(256) void knn3_kernel(
    const float* __restrict__ unknown,   // (B,N,3)
    const float* __restrict__ known,     // (B,M,3)
    int*   __restrict__ idx_out,         // (B,N,3)
    float* __restrict__ w_out)           // (B,N,3)
{
    __shared__ float kp[MM * 3];         // 48 KB
    __shared__ float md[128][3];
    __shared__ int   mi[128][3];

    const int b    = blockIdx.y;
    const int tid  = threadIdx.x;
    const int q    = tid & 127;
    const int half = tid >> 7;
    const int n    = blockIdx.x * 128 + q;

    const float* kb = known + (size_t)b * MM * 3;
    for (int f = tid; f < MM * 3; f += 256) kp[f] = kb[f];
    __syncthreads();

    const float ux = unknown[((size_t)b * NN + n) * 3 + 0];
    const float uy = unknown[((size_t)b * NN + n) * 3 + 1];
    const float uz = unknown[((size_t)b * NN + n) * 3 + 2];

    float v0 = 3e38f, v1 = 3e38f, v2 = 3e38f;
    int   j0 = 0,     j1 = 0,     j2 = 0;
    const int mlo = half * (MM / 2);
    const int mhi = mlo + (MM / 2);
    for (int m = mlo; m < mhi; ++m) {
        float dx = ux - kp[m * 3 + 0];
        float dy = uy - kp[m * 3 + 1];
        float dz = uz - kp[m * 3 + 2];
        float d2 = fmaf(dx, dx, fmaf(dy, dy, dz * dz));
        if (d2 < v2) {
            if (d2 < v1) {
                v2 = v1; j2 = j1;
                if (d2 < v0) { v1 = v0; j1 = j0; v0 = d2; j0 = m; }
                else         { v1 = d2; j1 = m; }
            } else { v2 = d2; j2 = m; }
        }
    }

    if (half) {
        md[q][0] = v0; md[q][1] = v1; md[q][2] = v2;
        mi[q][0] = j0; mi[q][1] = j1; mi[q][2] = j2;
    }
    __syncthreads();

    if (!half) {
        float av[3] = {v0, v1, v2};  int aj[3] = {j0, j1, j2};
        float cv[3] = {md[q][0], md[q][1], md[q][2]};
        int   cj[3] = {mi[q][0], mi[q][1], mi[q][2]};
        float rv[3]; int rj[3];
        int ai = 0, ci = 0;
        #pragma unroll
        for (int k = 0; k < 3; ++k) {
            // strict < : lower half (lower indices) wins ties, matching top_k
            if (cv[ci] < av[ai]) { rv[k] = cv[ci]; rj[k] = cj[ci]; ++ci; }
            else                 { rv[k] = av[ai]; rj[k] = aj[ai]; ++ai; }
        }
        float d0 = sqrtf(fmaxf(rv[0], 0.f));
        float d1 = sqrtf(fmaxf(rv[1], 0.f));
        float d2 = sqrtf(fmaxf(rv[2], 0.f));
        float r0 = 1.f / (d0 + 1e-8f);
        float r1 = 1.f / (d1 + 1e-8f);
        float r2 = 1.f / (d2 + 1e-8f);
        float s  = r0 + r1 + r2;
        const size_t base = ((size_t)b * NN + n) * 3;
        idx_out[base + 0] = rj[0]; idx_out[base + 1] = rj[1]; idx_out[base + 2] = rj[2];
        w_out[base + 0] = r0 / s;  w_out[base + 1] = r1 / s;  w_out[base + 2] = r2 / s;
    }
}

// ------------- Kernel B: gather-interp + concat + 2-layer MLP -------------
// grid: (NN/TILE, BB), block: 256. One 16-point tile per block.
__global__ __launch_bounds__(256) void fp_mlp_kernel(
    const float* __restrict__ unknow_feats, // (B,C1,N)
    const float* __restrict__ known_feats,  // (B,C2,M)
    const float* __restrict__ W1,           // (H1, CIN)
    const float* __restrict__ b1,           // (H1)
    const float* __restrict__ W2,           // (H2, H1)
    const float* __restrict__ b2,           // (H2)
    const int*   __restrict__ idx,          // (B,N,3)
    const float* __restrict__ wgt,          // (B,N,3)
    float* __restrict__ out)                // (B,H2,N)
{
    __shared__ float Xs[CIN][TILE];      // 24 KB, reads are wave-broadcast
    __shared__ float Hs[H1][TILE + 1];   // pad: conflict-free row writes
    __shared__ int   Is[TILE * 3];
    __shared__ float Ws[TILE * 3];

    const int b   = blockIdx.y;
    const int n0  = blockIdx.x * TILE;
    const int tid = threadIdx.x;

    if (tid < TILE * 3) {
        const size_t base = ((size_t)b * NN + n0) * 3;
        Is[tid] = idx[base + tid];
        Ws[tid] = wgt[base + tid];
    }
    __syncthreads();

    // interpolated channels 0..C2-1
    for (int e = tid; e < C2 * TILE; e += 256) {
        int c = e >> 4, p = e & (TILE - 1);
        int   i0 = Is[p * 3 + 0], i1 = Is[p * 3 + 1], i2 = Is[p * 3 + 2];
        float w0 = Ws[p * 3 + 0], w1 = Ws[p * 3 + 1], w2 = Ws[p * 3 + 2];
        const float* kf = known_feats + ((size_t)b * C2 + c) * MM;
        Xs[c][p] = w0 * kf[i0] + w1 * kf[i1] + w2 * kf[i2];
    }
    // passthrough channels C2..C2+C1-1
    for (int e = tid; e < C1 * TILE; e += 256) {
        int c = e >> 4, p = e & (TILE - 1);
        Xs[C2 + c][p] = unknow_feats[((size_t)b * C1 + c) * NN + n0 + p];
    }
    __syncthreads();

    // layer 1: thread o computes h[o][0..15]
    {
        const int o = tid;
        float acc[TILE];
        const float bias = b1[o];
        #pragma unroll
        for (int p = 0; p < TILE; ++p) acc[p] = bias;
        const float* w = W1 + (size_t)o * CIN;
        #pragma unroll 4
        for (int c = 0; c < CIN; ++c) {
            float wc = w[c];
            #pragma unroll
            for (int p = 0; p < TILE; ++p) acc[p] = fmaf(wc, Xs[c][p], acc[p]);
        }
        #pragma unroll
        for (int p = 0; p < TILE; ++p) Hs[o][p] = fmaxf(acc[p], 0.f);
    }
    __syncthreads();

    // layer 2: threads 0..127, thread o computes out[o][0..15]
    if (tid < H2) {
        const int o = tid;
        float acc[TILE];
        const float bias = b2[o];
        #pragma unroll
        for (int p = 0; p < TILE; ++p) acc[p] = bias;
        const float* w = W2 + (size_t)o * H1;
        #pragma unroll 4
        for (int c = 0; c < H1; ++c) {
            float wc = w[c];
            #pragma unroll
            for (int p = 0; p < TILE; ++p) acc[p] = fmaf(wc, Hs[c][p], acc[p]);
        }
        float* op = out + ((size_t)b * H2 + o) * NN + n0;
        #pragma unroll
        for (int p = 0; p < TILE; ++p) op[p] = fmaxf(acc[p], 0.f);
    }
}

extern "C" void kernel_launch(void* const* d_in, const int* in_sizes, int n_in,
                              void* d_out, int out_size, void* d_ws, size_t ws_size,
                              hipStream_t stream) {
    const float* unknown      = (const float*)d_in[0];
    const float* known        = (const float*)d_in[1];
    const float* unknow_feats = (const float*)d_in[2];
    const float* known_feats  = (const float*)d_in[3];
    const float* W1           = (const float*)d_in[4];
    const float* b1           = (const float*)d_in[5];
    const float* W2           = (const float*)d_in[6];
    const float* b2           = (const float*)d_in[7];
    float* out = (float*)d_out;

    float* wgt = (float*)d_ws;                                   // B*N*3 floats
    int*   idx = (int*)((char*)d_ws + (size_t)BB * NN * 3 * 4);  // B*N*3 ints

    dim3 gA(NN / 128, BB);
    knn3_kernel<<<gA, 256, 0, stream>>>(unknown, known, idx, wgt);

    dim3 gB(NN / TILE, BB);
    fp_mlp_kernel<<<gB, 256, 0, stream>>>(unknow_feats, known_feats,
                                          W1, b1, W2, b2, idx, wgt, out);
}

// Round 2
// 209.916 us; speedup vs baseline: 3.4376x; 3.4376x over previous
//
#include <hip/hip_runtime.h>

// PointNet2 FP: 3-NN interp + concat + MLP(384->256->128) via bf16 MFMA
#define BB 2
#define NN 16384
#define MM 4096
#define C1 128
#define C2 256
#define CIN 384
#define H1 256
#define H2 128
#define PT 32          // points per block in fused MLP kernel

typedef __attribute__((ext_vector_type(8))) short bf16x8;
typedef __attribute__((ext_vector_type(4))) float f32x4;
typedef __attribute__((ext_vector_type(4))) short short4v;

__device__ __forceinline__ short f32_to_bf16(float x) {
    unsigned u = __float_as_uint(x);
    u += 0x7fffu + ((u >> 16) & 1u);   // RNE
    return (short)(u >> 16);
}

// ---------------- Kernel A: 3-NN, 8 threads/query ----------------
// grid (NN/32, BB), block 256. LDS SoA coords; float4 scan, bank-rotated.
__global__ __launch_bounds__(256) void knn3_kernel(
    const float* __restrict__ unknown,   // (B,N,3)
    const float* __restrict__ known,     // (B,M,3)
    int*   __restrict__ idx_out,         // (B,N,3)
    float* __restrict__ w_out)           // (B,N,3)
{
    __shared__ float kx[MM], ky[MM], kz[MM];   // 48 KB
    __shared__ float sd[32][8][3];
    __shared__ int   si[32][8][3];

    const int b   = blockIdx.y;
    const int tid = threadIdx.x;
    const int q   = tid >> 3;       // query within block (0..31)
    const int t   = tid & 7;        // scanner (0..7)
    const int n   = blockIdx.x * 32 + q;

    const float* kb = known + (size_t)b * MM * 3;
    for (int m = tid; m < MM; m += 256) {
        kx[m] = kb[3 * m + 0];
        ky[m] = kb[3 * m + 1];
        kz[m] = kb[3 * m + 2];
    }
    __syncthreads();

    const float ux = unknown[((size_t)b * NN + n) * 3 + 0];
    const float uy = unknown[((size_t)b * NN + n) * 3 + 1];
    const float uz = unknown[((size_t)b * NN + n) * 3 + 2];

    float v0 = 3e38f, v1 = 3e38f, v2 = 3e38f;
    int   j0 = 0,     j1 = 0,     j2 = 0;
    const int base = t * 512;
    #pragma unroll 2
    for (int i = 0; i < 512; i += 4) {
        const int ii = (i + 4 * t) & 511;      // bank rotation
        const int m  = base + ii;
        const float4 x4 = *(const float4*)&kx[m];
        const float4 y4 = *(const float4*)&ky[m];
        const float4 z4 = *(const float4*)&kz[m];
        #pragma unroll
        for (int j = 0; j < 4; ++j) {
            float dx = ux - ((const float*)&x4)[j];
            float dy = uy - ((const float*)&y4)[j];
            float dz = uz - ((const float*)&z4)[j];
            float d2 = fmaf(dx, dx, fmaf(dy, dy, dz * dz));
            if (d2 < v2) {
                if (d2 < v1) {
                    v2 = v1; j2 = j1;
                    if (d2 < v0) { v1 = v0; j1 = j0; v0 = d2; j0 = m + j; }
                    else         { v1 = d2; j1 = m + j; }
                } else { v2 = d2; j2 = m + j; }
            }
        }
    }
    sd[q][t][0] = v0; sd[q][t][1] = v1; sd[q][t][2] = v2;
    si[q][t][0] = j0; si[q][t][1] = j1; si[q][t][2] = j2;
    __syncthreads();

    if (t == 0) {
        float rv0 = 3e38f, rv1 = 3e38f, rv2 = 3e38f;
        int   rj0 = 0,     rj1 = 0,     rj2 = 0;
        #pragma unroll
        for (int tt = 0; tt < 8; ++tt) {
            #pragma unroll
            for (int k = 0; k < 3; ++k) {
                float d = sd[q][tt][k];
                int   j = si[q][tt][k];
                if (d < rv2) {
                    if (d < rv1) {
                        rv2 = rv1; rj2 = rj1;
                        if (d < rv0) { rv1 = rv0; rj1 = rj0; rv0 = d; rj0 = j; }
                        else         { rv1 = d; rj1 = j; }
                    } else { rv2 = d; rj2 = j; }
                }
            }
        }
        float d0 = sqrtf(fmaxf(rv0, 0.f));
        float d1 = sqrtf(fmaxf(rv1, 0.f));
        float d2 = sqrtf(fmaxf(rv2, 0.f));
        float r0 = 1.f / (d0 + 1e-8f);
        float r1 = 1.f / (d1 + 1e-8f);
        float r2 = 1.f / (d2 + 1e-8f);
        float s  = r0 + r1 + r2;
        const size_t ob = ((size_t)b * NN + n) * 3;
        idx_out[ob + 0] = rj0; idx_out[ob + 1] = rj1; idx_out[ob + 2] = rj2;
        w_out[ob + 0] = r0 / s; w_out[ob + 1] = r1 / s; w_out[ob + 2] = r2 / s;
    }
}

// ---------------- Kernel T: transpose known_feats (B,C2,M)->(B,M,C2) ----
__global__ __launch_bounds__(256) void transpose_kernel(
    const float* __restrict__ KF, float* __restrict__ KT)
{
    __shared__ float tl[32][33];
    const int b  = blockIdx.z;
    const int m0 = blockIdx.x * 32;
    const int c0 = blockIdx.y * 32;
    const int tx = threadIdx.x & 31;
    const int ty = threadIdx.x >> 5;    // 0..7
    #pragma unroll
    for (int r = 0; r < 4; ++r) {
        int c = ty + r * 8;
        tl[c][tx] = KF[((size_t)b * C2 + c0 + c) * MM + m0 + tx];
    }
    __syncthreads();
    #pragma unroll
    for (int r = 0; r < 4; ++r) {
        int m = ty + r * 8;
        KT[((size_t)b * MM + m0 + m) * C2 + c0 + tx] = tl[tx][m];
    }
}

// ---------------- Kernel W: cast weights to bf16 ----------------
__global__ __launch_bounds__(256) void wcast_kernel(
    const float* __restrict__ W1, const float* __restrict__ W2,
    short* __restrict__ W1b, short* __restrict__ W2b)
{
    int i = blockIdx.x * 256 + threadIdx.x;
    if (i < H1 * CIN) W1b[i] = f32_to_bf16(W1[i]);
    if (i < H2 * H1)  W2b[i] = f32_to_bf16(W2[i]);
}

// ---------------- Kernel B: fused gather-interp + 2-layer MFMA MLP -------
// grid 1024 (= B * N/PT), block 256 (4 waves).
// LDS: Xs[PT][392] bf16 (pad 8 -> 2-way-free b128 reads), Hs[PT][264] bf16.
__global__ __launch_bounds__(256, 3) void fp_mlp_mfma_kernel(
    const float* __restrict__ unknow_feats, // (B,C1,N)
    const float* __restrict__ KT,           // (B,M,C2)
    const short* __restrict__ W1b,          // (H1,CIN) bf16
    const float* __restrict__ b1,
    const short* __restrict__ W2b,          // (H2,H1) bf16
    const float* __restrict__ b2,
    const int*   __restrict__ idx,          // (B,N,3)
    const float* __restrict__ wgt,          // (B,N,3)
    float* __restrict__ out)                // (B,H2,N)
{
    #define XROW 392   // 384 + 8 pad (16B-aligned rows)
    #define HROW 264   // 256 + 8 pad
    __shared__ short Xs[PT][XROW];
    __shared__ short Hs[PT][HROW];
    __shared__ int   Is[PT * 3];
    __shared__ float Ws[PT * 3];

    const int tid  = threadIdx.x;
    const int blocks_per_b = NN / PT;             // 512
    const int b    = blockIdx.x / blocks_per_b;
    const int n0   = (blockIdx.x % blocks_per_b) * PT;
    const int w    = tid >> 6;                    // wave 0..3
    const int lane = tid & 63;
    const int lr   = lane & 15;
    const int lq   = lane >> 4;

    if (tid < PT * 3) {
        const size_t base = ((size_t)b * NN + n0) * 3;
        Is[tid] = idx[base + tid];
        Ws[tid] = wgt[base + tid];
    }
    __syncthreads();

    // ---- build X tile: rows = points, cols = [interp(256) ; unk(128)] ----
    {
        const float* KTb = KT + (size_t)b * MM * C2;
        const int c = tid;            // 0..255, coalesced over c
        #pragma unroll 4
        for (int p = 0; p < PT; ++p) {
            const int   i0 = Is[3 * p + 0], i1 = Is[3 * p + 1], i2 = Is[3 * p + 2];
            const float w0 = Ws[3 * p + 0], w1 = Ws[3 * p + 1], w2 = Ws[3 * p + 2];
            float v = w0 * KTb[(size_t)i0 * C2 + c]
                    + w1 * KTb[(size_t)i1 * C2 + c]
                    + w2 * KTb[(size_t)i2 * C2 + c];
            Xs[p][c] = f32_to_bf16(v);
        }
        for (int e = tid; e < C1 * PT; e += 256) {
            int cc = e >> 5, p = e & (PT - 1);   // consecutive tid -> consecutive p
            Xs[p][C2 + cc] = f32_to_bf16(unknow_feats[((size_t)b * C1 + cc) * NN + n0 + p]);
        }
    }
    __syncthreads();

    // ---- GEMM1: H[256 x PT] = ReLU(W1 * X + b1), wave w -> o in [64w,64w+64) ----
    {
        f32x4 acc[4][2];
        #pragma unroll
        for (int t = 0; t < 4; ++t)
            #pragma unroll
            for (int p = 0; p < 2; ++p) acc[t][p] = (f32x4){0.f, 0.f, 0.f, 0.f};

        for (int k0 = 0; k0 < CIN; k0 += 32) {
            bf16x8 a[4], x[2];
            #pragma unroll
            for (int t = 0; t < 4; ++t)
                a[t] = *(const bf16x8*)(W1b + (size_t)(w * 64 + t * 16 + lr) * CIN + k0 + lq * 8);
            #pragma unroll
            for (int p = 0; p < 2; ++p)
                x[p] = *(bf16x8*)&Xs[p * 16 + lr][k0 + lq * 8];
            #pragma unroll
            for (int t = 0; t < 4; ++t)
                #pragma unroll
                for (int p = 0; p < 2; ++p)
                    acc[t][p] = __builtin_amdgcn_mfma_f32_16x16x32_bf16(a[t], x[p], acc[t][p], 0, 0, 0);
        }
        // epilogue: C row=(lq*4+r), col=lr  -> Hs[point][channel]
        #pragma unroll
        for (int t = 0; t < 4; ++t) {
            const int obase = w * 64 + t * 16 + lq * 4;
            float bb0 = b1[obase + 0], bb1 = b1[obase + 1],
                  bb2 = b1[obase + 2], bb3 = b1[obase + 3];
            #pragma unroll
            for (int p = 0; p < 2; ++p) {
                short4v hv;
                hv.x = f32_to_bf16(fmaxf(acc[t][p].x + bb0, 0.f));
                hv.y = f32_to_bf16(fmaxf(acc[t][p].y + bb1, 0.f));
                hv.z = f32_to_bf16(fmaxf(acc[t][p].z + bb2, 0.f));
                hv.w = f32_to_bf16(fmaxf(acc[t][p].w + bb3, 0.f));
                *(short4v*)&Hs[p * 16 + lr][obase] = hv;
            }
        }
    }
    __syncthreads();

    // ---- GEMM2: Out[128 x PT] = ReLU(W2 * H + b2), wave w -> o in [32w,32w+32) ----
    {
        f32x4 acc[2][2];
        #pragma unroll
        for (int t = 0; t < 2; ++t)
            #pragma unroll
            for (int p = 0; p < 2; ++p) acc[t][p] = (f32x4){0.f, 0.f, 0.f, 0.f};

        for (int k0 = 0; k0 < H1; k0 += 32) {
            bf16x8 a[2], h[2];
            #pragma unroll
            for (int t = 0; t < 2; ++t)
                a[t] = *(const bf16x8*)(W2b + (size_t)(w * 32 + t * 16 + lr) * H1 + k0 + lq * 8);
            #pragma unroll
            for (int p = 0; p < 2; ++p)
                h[p] = *(bf16x8*)&Hs[p * 16 + lr][k0 + lq * 8];
            #pragma unroll
            for (int t = 0; t < 2; ++t)
                #pragma unroll
                for (int p = 0; p < 2; ++p)
                    acc[t][p] = __builtin_amdgcn_mfma_f32_16x16x32_bf16(a[t], h[p], acc[t][p], 0, 0, 0);
        }
        #pragma unroll
        for (int t = 0; t < 2; ++t) {
            const int obase = w * 32 + t * 16 + lq * 4;
            #pragma unroll
            for (int p = 0; p < 2; ++p) {
                const int n = n0 + p * 16 + lr;
                #pragma unroll
                for (int r = 0; r < 4; ++r) {
                    const int o = obase + r;
                    out[((size_t)b * H2 + o) * NN + n] =
                        fmaxf(((const float*)&acc[t][p])[r] + b2[o], 0.f);
                }
            }
        }
    }
    #undef XROW
    #undef HROW
}

extern "C" void kernel_launch(void* const* d_in, const int* in_sizes, int n_in,
                              void* d_out, int out_size, void* d_ws, size_t ws_size,
                              hipStream_t stream) {
    const float* unknown      = (const float*)d_in[0];
    const float* known        = (const float*)d_in[1];
    const float* unknow_feats = (const float*)d_in[2];
    const float* known_feats  = (const float*)d_in[3];
    const float* W1           = (const float*)d_in[4];
    const float* b1           = (const float*)d_in[5];
    const float* W2           = (const float*)d_in[6];
    const float* b2           = (const float*)d_in[7];
    float* out = (float*)d_out;

    char* ws = (char*)d_ws;
    int*   idx = (int*)(ws);                       // 393216 B
    float* wgt = (float*)(ws + 393216);            // 393216 B
    short* W1b = (short*)(ws + 786432);            // 196608 B
    short* W2b = (short*)(ws + 983040);            // 65536 B
    float* KT  = (float*)(ws + 1048576);           // 8388608 B

    dim3 gK(NN / 32, BB);
    knn3_kernel<<<gK, 256, 0, stream>>>(unknown, known, idx, wgt);

    dim3 gT(MM / 32, C2 / 32, BB);
    transpose_kernel<<<gT, 256, 0, stream>>>(known_feats, KT);

    wcast_kernel<<<(H1 * CIN + 255) / 256, 256, 0, stream>>>(W1, W2, W1b, W2b);

    fp_mlp_mfma_kernel<<<BB * (NN / PT), 256, 0, stream>>>(
        unknow_feats, KT, W1b, b1, W2b, b2, idx, wgt, out);
}

// Round 3
// 202.635 us; speedup vs baseline: 3.5611x; 1.0359x over previous
//
#include <hip/hip_runtime.h>

// PointNet2 FP: 3-NN interp + concat + MLP(384->256->128) via bf16 MFMA
#define BB 2
#define NN 16384
#define MM 4096
#define C1 128
#define C2 256
#define CIN 384
#define H1 256
#define H2 128
#define PT 32          // points per block in fused MLP kernel

typedef __attribute__((ext_vector_type(8))) short bf16x8;
typedef __attribute__((ext_vector_type(4))) float f32x4;
typedef __attribute__((ext_vector_type(4))) short short4v;

__device__ __forceinline__ short f32_to_bf16(float x) {
    unsigned u = __float_as_uint(x);
    u += 0x7fffu + ((u >> 16) & 1u);   // RNE
    return (short)(u >> 16);
}

// ---------------- Kernel P: prep — cast weights to bf16 + pack known ------
__global__ __launch_bounds__(256) void prep_kernel(
    const float* __restrict__ W1, const float* __restrict__ W2,
    const float* __restrict__ known,
    short* __restrict__ W1b, short* __restrict__ W2b,
    float4* __restrict__ kpk)           // (B*M) {x,y,z,|k|^2}
{
    int i = blockIdx.x * 256 + threadIdx.x;
    if (i < H1 * CIN) W1b[i] = f32_to_bf16(W1[i]);
    if (i < H2 * H1)  W2b[i] = f32_to_bf16(W2[i]);
    if (i < BB * MM) {
        float x = known[3 * i + 0], y = known[3 * i + 1], z = known[3 * i + 2];
        kpk[i] = make_float4(x, y, z, fmaf(x, x, fmaf(y, y, z * z)));
    }
}

// ---------------- Kernel A: 3-NN via wave-uniform scalar candidate stream -
// block 512 (8 waves). Each block: 64 queries (lane-indexed, same for all
// waves); wave w scans candidates [w*512, w*512+512) with SCALAR loads
// (address is wave-uniform -> s_load_dwordx4, off the VALU pipe).
// score = |k|^2 - 2 u.k  (monotone in d2; same expansion as reference).
__global__ __launch_bounds__(512) void knn3_kernel(
    const float* __restrict__ unknown,   // (B,N,3)
    const float4* __restrict__ kpk,      // (B,M) packed
    int*   __restrict__ idx_out,         // (B,N,3)
    float* __restrict__ w_out)           // (B,N,3)
{
    __shared__ float pd[8][64][3];
    __shared__ int   pi[8][64][3];

    const int b    = blockIdx.y;
    const int tid  = threadIdx.x;
    const int lane = tid & 63;
    const int wv   = __builtin_amdgcn_readfirstlane(tid >> 6);  // uniform 0..7
    const int n    = blockIdx.x * 64 + lane;

    const float ux = unknown[((size_t)b * NN + n) * 3 + 0];
    const float uy = unknown[((size_t)b * NN + n) * 3 + 1];
    const float uz = unknown[((size_t)b * NN + n) * 3 + 2];
    const float ax = -2.f * ux, ay = -2.f * uy, az = -2.f * uz;
    const float un = fmaf(ux, ux, fmaf(uy, uy, uz * uz));

    const int mbase = wv * (MM / 8);
    const float4* __restrict__ kp = kpk + (size_t)b * MM + mbase;

    float v0 = 3e38f, v1 = 3e38f, v2 = 3e38f;
    int   j0 = 0,     j1 = 0,     j2 = 0;
    for (int m = 0; m < MM / 8; m += 8) {
        #pragma unroll
        for (int u = 0; u < 8; ++u) {
            const float4 k = kp[m + u];          // wave-uniform -> s_load
            float sc = fmaf(ax, k.x, fmaf(ay, k.y, fmaf(az, k.z, k.w)));
            if (sc < v2) {
                const int mm = mbase + m + u;
                if (sc < v1) {
                    v2 = v1; j2 = j1;
                    if (sc < v0) { v1 = v0; j1 = j0; v0 = sc; j0 = mm; }
                    else         { v1 = sc; j1 = mm; }
                } else { v2 = sc; j2 = mm; }
            }
        }
    }
    pd[wv][lane][0] = v0; pd[wv][lane][1] = v1; pd[wv][lane][2] = v2;
    pi[wv][lane][0] = j0; pi[wv][lane][1] = j1; pi[wv][lane][2] = j2;
    __syncthreads();

    if (tid < 64) {
        float r0 = 3e38f, r1 = 3e38f, r2 = 3e38f;
        int   q0 = 0,     q1 = 0,     q2 = 0;
        #pragma unroll
        for (int ww = 0; ww < 8; ++ww) {
            #pragma unroll
            for (int k = 0; k < 3; ++k) {
                float d = pd[ww][lane][k];
                int   j = pi[ww][lane][k];
                // strict <: earlier (lower-m) partials win ties, matching top_k
                if (d < r2) {
                    if (d < r1) {
                        r2 = r1; q2 = q1;
                        if (d < r0) { r1 = r0; q1 = q0; r0 = d; q0 = j; }
                        else        { r1 = d; q1 = j; }
                    } else { r2 = d; q2 = j; }
                }
            }
        }
        float d0 = sqrtf(fmaxf(r0 + un, 0.f));
        float d1 = sqrtf(fmaxf(r1 + un, 0.f));
        float d2 = sqrtf(fmaxf(r2 + un, 0.f));
        float i0 = 1.f / (d0 + 1e-8f);
        float i1 = 1.f / (d1 + 1e-8f);
        float i2 = 1.f / (d2 + 1e-8f);
        float s  = i0 + i1 + i2;
        const size_t ob = ((size_t)b * NN + n) * 3;
        idx_out[ob + 0] = q0; idx_out[ob + 1] = q1; idx_out[ob + 2] = q2;
        w_out[ob + 0] = i0 / s; w_out[ob + 1] = i1 / s; w_out[ob + 2] = i2 / s;
    }
}

// ---------------- Kernel T: transpose known_feats (B,C2,M)->(B,M,C2) ----
__global__ __launch_bounds__(256) void transpose_kernel(
    const float* __restrict__ KF, float* __restrict__ KT)
{
    __shared__ float tl[32][33];
    const int b  = blockIdx.z;
    const int m0 = blockIdx.x * 32;
    const int c0 = blockIdx.y * 32;
    const int tx = threadIdx.x & 31;
    const int ty = threadIdx.x >> 5;    // 0..7
    #pragma unroll
    for (int r = 0; r < 4; ++r) {
        int c = ty + r * 8;
        tl[c][tx] = KF[((size_t)b * C2 + c0 + c) * MM + m0 + tx];
    }
    __syncthreads();
    #pragma unroll
    for (int r = 0; r < 4; ++r) {
        int m = ty + r * 8;
        KT[((size_t)b * MM + m0 + m) * C2 + c0 + tx] = tl[tx][m];
    }
}

// ---------------- Kernel B: fused gather-interp + 2-layer MFMA MLP -------
// grid 1024 (= B * N/PT), block 256 (4 waves).
__global__ __launch_bounds__(256, 3) void fp_mlp_mfma_kernel(
    const float* __restrict__ unknow_feats, // (B,C1,N)
    const float* __restrict__ KT,           // (B,M,C2)
    const short* __restrict__ W1b,          // (H1,CIN) bf16
    const float* __restrict__ b1,
    const short* __restrict__ W2b,          // (H2,H1) bf16
    const float* __restrict__ b2,
    const int*   __restrict__ idx,          // (B,N,3)
    const float* __restrict__ wgt,          // (B,N,3)
    float* __restrict__ out)                // (B,H2,N)
{
    #define XROW 392   // 384 + 8 pad
    #define HROW 264   // 256 + 8 pad
    __shared__ short Xs[PT][XROW];
    __shared__ short Hs[PT][HROW];
    __shared__ int   Is[PT * 3];
    __shared__ float Ws[PT * 3];

    const int tid  = threadIdx.x;
    const int blocks_per_b = NN / PT;             // 512
    const int b    = blockIdx.x / blocks_per_b;
    const int n0   = (blockIdx.x % blocks_per_b) * PT;
    const int w    = tid >> 6;                    // wave 0..3
    const int lane = tid & 63;
    const int lr   = lane & 15;
    const int lq   = lane >> 4;

    if (tid < PT * 3) {
        const size_t base = ((size_t)b * NN + n0) * 3;
        Is[tid] = idx[base + tid];
        Ws[tid] = wgt[base + tid];
    }
    __syncthreads();

    {
        const float* KTb = KT + (size_t)b * MM * C2;
        const int c = tid;            // 0..255, coalesced over c
        #pragma unroll 4
        for (int p = 0; p < PT; ++p) {
            const int   i0 = Is[3 * p + 0], i1 = Is[3 * p + 1], i2 = Is[3 * p + 2];
            const float w0 = Ws[3 * p + 0], w1 = Ws[3 * p + 1], w2 = Ws[3 * p + 2];
            float v = w0 * KTb[(size_t)i0 * C2 + c]
                    + w1 * KTb[(size_t)i1 * C2 + c]
                    + w2 * KTb[(size_t)i2 * C2 + c];
            Xs[p][c] = f32_to_bf16(v);
        }
        for (int e = tid; e < C1 * PT; e += 256) {
            int cc = e >> 5, p = e & (PT - 1);
            Xs[p][C2 + cc] = f32_to_bf16(unknow_feats[((size_t)b * C1 + cc) * NN + n0 + p]);
        }
    }
    __syncthreads();

    // GEMM1: H[256 x PT] = ReLU(W1 * X + b1)
    {
        f32x4 acc[4][2];
        #pragma unroll
        for (int t = 0; t < 4; ++t)
            #pragma unroll
            for (int p = 0; p < 2; ++p) acc[t][p] = (f32x4){0.f, 0.f, 0.f, 0.f};

        for (int k0 = 0; k0 < CIN; k0 += 32) {
            bf16x8 a[4], x[2];
            #pragma unroll
            for (int t = 0; t < 4; ++t)
                a[t] = *(const bf16x8*)(W1b + (size_t)(w * 64 + t * 16 + lr) * CIN + k0 + lq * 8);
            #pragma unroll
            for (int p = 0; p < 2; ++p)
                x[p] = *(bf16x8*)&Xs[p * 16 + lr][k0 + lq * 8];
            #pragma unroll
            for (int t = 0; t < 4; ++t)
                #pragma unroll
                for (int p = 0; p < 2; ++p)
                    acc[t][p] = __builtin_amdgcn_mfma_f32_16x16x32_bf16(a[t], x[p], acc[t][p], 0, 0, 0);
        }
        #pragma unroll
        for (int t = 0; t < 4; ++t) {
            const int obase = w * 64 + t * 16 + lq * 4;
            float bb0 = b1[obase + 0], bb1 = b1[obase + 1],
                  bb2 = b1[obase + 2], bb3 = b1[obase + 3];
            #pragma unroll
            for (int p = 0; p < 2; ++p) {
                short4v hv;
                hv.x = f32_to_bf16(fmaxf(acc[t][p].x + bb0, 0.f));
                hv.y = f32_to_bf16(fmaxf(acc[t][p].y + bb1, 0.f));
                hv.z = f32_to_bf16(fmaxf(acc[t][p].z + bb2, 0.f));
                hv.w = f32_to_bf16(fmaxf(acc[t][p].w + bb3, 0.f));
                *(short4v*)&Hs[p * 16 + lr][obase] = hv;
            }
        }
    }
    __syncthreads();

    // GEMM2: Out[128 x PT] = ReLU(W2 * H + b2)
    {
        f32x4 acc[2][2];
        #pragma unroll
        for (int t = 0; t < 2; ++t)
            #pragma unroll
            for (int p = 0; p < 2; ++p) acc[t][p] = (f32x4){0.f, 0.f, 0.f, 0.f};

        for (int k0 = 0; k0 < H1; k0 += 32) {
            bf16x8 a[2], h[2];
            #pragma unroll
            for (int t = 0; t < 2; ++t)
                a[t] = *(const bf16x8*)(W2b + (size_t)(w * 32 + t * 16 + lr) * H1 + k0 + lq * 8);
            #pragma unroll
            for (int p = 0; p < 2; ++p)
                h[p] = *(bf16x8*)&Hs[p * 16 + lr][k0 + lq * 8];
            #pragma unroll
            for (int t = 0; t < 2; ++t)
                #pragma unroll
                for (int p = 0; p < 2; ++p)
                    acc[t][p] = __builtin_amdgcn_mfma_f32_16x16x32_bf16(a[t], h[p], acc[t][p], 0, 0, 0);
        }
        #pragma unroll
        for (int t = 0; t < 2; ++t) {
            const int obase = w * 32 + t * 16 + lq * 4;
            #pragma unroll
            for (int p = 0; p < 2; ++p) {
                const int n = n0 + p * 16 + lr;
                #pragma unroll
                for (int r = 0; r < 4; ++r) {
                    const int o = obase + r;
                    out[((size_t)b * H2 + o) * NN + n] =
                        fmaxf(((const float*)&acc[t][p])[r] + b2[o], 0.f);
                }
            }
        }
    }
    #undef XROW
    #undef HROW
}

extern "C" void kernel_launch(void* const* d_in, const int* in_sizes, int n_in,
                              void* d_out, int out_size, void* d_ws, size_t ws_size,
                              hipStream_t stream) {
    const float* unknown      = (const float*)d_in[0];
    const float* known        = (const float*)d_in[1];
    const float* unknow_feats = (const float*)d_in[2];
    const float* known_feats  = (const float*)d_in[3];
    const float* W1           = (const float*)d_in[4];
    const float* b1           = (const float*)d_in[5];
    const float* W2           = (const float*)d_in[6];
    const float* b2           = (const float*)d_in[7];
    float* out = (float*)d_out;

    char* ws = (char*)d_ws;
    int*    idx = (int*)(ws);                      // 393216 B
    float*  wgt = (float*)(ws + 393216);           // 393216 B
    short*  W1b = (short*)(ws + 786432);           // 196608 B
    short*  W2b = (short*)(ws + 983040);           // 65536 B
    float4* kpk = (float4*)(ws + 1048576);         // 131072 B
    float*  KT  = (float*)(ws + 1179648);          // 8388608 B

    prep_kernel<<<(H1 * CIN + 255) / 256, 256, 0, stream>>>(W1, W2, known, W1b, W2b, kpk);

    dim3 gK(NN / 64, BB);
    knn3_kernel<<<gK, 512, 0, stream>>>(unknown, kpk, idx, wgt);

    dim3 gT(MM / 32, C2 / 32, BB);
    transpose_kernel<<<gT, 256, 0, stream>>>(known_feats, KT);

    fp_mlp_mfma_kernel<<<BB * (NN / PT), 256, 0, stream>>>(
        unknow_feats, KT, W1b, b1, W2b, b2, idx, wgt, out);
}

// Round 4
// 195.459 us; speedup vs baseline: 3.6919x; 1.0367x over previous
//
#include <hip/hip_runtime.h>
#include <hip/hip_bf16.h>

// PointNet2 FP: 3-NN interp + concat + MLP(384->256->128) via bf16 MFMA
#define BB 2
#define NN 16384
#define MM 4096
#define C1 128
#define C2 256
#define CIN 384
#define H1 256
#define H2 128
#define PT 32          // points per block in fused MLP kernel

typedef __attribute__((ext_vector_type(8))) short bf16x8;
typedef __attribute__((ext_vector_type(4))) float f32x4;

__device__ __forceinline__ short f32_to_bf16(float x) {
    unsigned u = __float_as_uint(x);
    u += 0x7fffu + ((u >> 16) & 1u);   // RNE
    return (short)(u >> 16);
}
__device__ __forceinline__ unsigned pack_bf16x2(float a, float b) {
    __hip_bfloat162 h = __float22bfloat162_rn(make_float2(a, b));
    union { __hip_bfloat162 h; unsigned u; } cv;
    cv.h = h;
    return cv.u;
}

// ---------------- Kernel P: prep — cast weights to bf16 + pack known ------
__global__ __launch_bounds__(256) void prep_kernel(
    const float* __restrict__ W1, const float* __restrict__ W2,
    const float* __restrict__ known,
    short* __restrict__ W1b, short* __restrict__ W2b,
    float4* __restrict__ kpk)           // (B*M) {x,y,z,|k|^2}
{
    int i = blockIdx.x * 256 + threadIdx.x;
    if (i < H1 * CIN) W1b[i] = f32_to_bf16(W1[i]);
    if (i < H2 * H1)  W2b[i] = f32_to_bf16(W2[i]);
    if (i < BB * MM) {
        float x = known[3 * i + 0], y = known[3 * i + 1], z = known[3 * i + 2];
        kpk[i] = make_float4(x, y, z, fmaf(x, x, fmaf(y, y, z * z)));
    }
}

// ---------------- Kernel A: 3-NN, scalar candidate stream, branchless -----
// block 512 (8 waves): 64 queries (lanes), wave w scans candidates
// [w*512, w*512+512) via wave-uniform s_load_dwordx4. Branchless top-3:
// values fminf + 2x fmed3, indices cmp+cndmask. Strict < keeps lower index
// on ties (ascending scan), matching lax.top_k.
__global__ __launch_bounds__(512) void knn3_kernel(
    const float* __restrict__ unknown,   // (B,N,3)
    const float4* __restrict__ kpk,      // (B,M) packed
    int*   __restrict__ idx_out,         // (B,N,3)
    float* __restrict__ w_out)           // (B,N,3)
{
    __shared__ float pd[8][64][3];
    __shared__ int   pi[8][64][3];

    const int b    = blockIdx.y;
    const int tid  = threadIdx.x;
    const int lane = tid & 63;
    const int wv   = __builtin_amdgcn_readfirstlane(tid >> 6);  // uniform 0..7
    const int n    = blockIdx.x * 64 + lane;

    const float ux = unknown[((size_t)b * NN + n) * 3 + 0];
    const float uy = unknown[((size_t)b * NN + n) * 3 + 1];
    const float uz = unknown[((size_t)b * NN + n) * 3 + 2];
    const float ax = -2.f * ux, ay = -2.f * uy, az = -2.f * uz;
    const float un = fmaf(ux, ux, fmaf(uy, uy, uz * uz));

    const int mbase = wv * (MM / 8);
    const float4* __restrict__ kp = kpk + (size_t)b * MM + mbase;

    float v0 = 3e38f, v1 = 3e38f, v2 = 3e38f;
    int   j0 = 0,     j1 = 0,     j2 = 0;
    for (int m = 0; m < MM / 8; m += 8) {
        #pragma unroll
        for (int u = 0; u < 8; ++u) {
            const float4 k = kp[m + u];          // wave-uniform -> s_load
            float sc = fmaf(ax, k.x, fmaf(ay, k.y, fmaf(az, k.z, k.w)));
            const int mm = mbase + m + u;
            const bool lt0 = sc < v0;
            const bool lt1 = sc < v1;
            const bool lt2 = sc < v2;
            // sorted-insert network (reads olds before writes)
            v2 = __builtin_amdgcn_fmed3f(v1, sc, v2);
            j2 = lt1 ? j1 : (lt2 ? mm : j2);
            v1 = __builtin_amdgcn_fmed3f(v0, sc, v1);
            j1 = lt0 ? j0 : (lt1 ? mm : j1);
            v0 = fminf(sc, v0);
            j0 = lt0 ? mm : j0;
        }
    }
    pd[wv][lane][0] = v0; pd[wv][lane][1] = v1; pd[wv][lane][2] = v2;
    pi[wv][lane][0] = j0; pi[wv][lane][1] = j1; pi[wv][lane][2] = j2;
    __syncthreads();

    if (tid < 64) {
        float r0 = 3e38f, r1 = 3e38f, r2 = 3e38f;
        int   q0 = 0,     q1 = 0,     q2 = 0;
        #pragma unroll
        for (int ww = 0; ww < 8; ++ww) {
            #pragma unroll
            for (int k = 0; k < 3; ++k) {
                float d = pd[ww][lane][k];
                int   j = pi[ww][lane][k];
                const bool lt0 = d < r0;
                const bool lt1 = d < r1;
                const bool lt2 = d < r2;
                r2 = __builtin_amdgcn_fmed3f(r1, d, r2);
                q2 = lt1 ? q1 : (lt2 ? j : q2);
                r1 = __builtin_amdgcn_fmed3f(r0, d, r1);
                q1 = lt0 ? q0 : (lt1 ? j : q1);
                r0 = fminf(d, r0);
                q0 = lt0 ? j : q0;
            }
        }
        float d0 = sqrtf(fmaxf(r0 + un, 0.f));
        float d1 = sqrtf(fmaxf(r1 + un, 0.f));
        float d2 = sqrtf(fmaxf(r2 + un, 0.f));
        float i0 = 1.f / (d0 + 1e-8f);
        float i1 = 1.f / (d1 + 1e-8f);
        float i2 = 1.f / (d2 + 1e-8f);
        float s  = i0 + i1 + i2;
        const size_t ob = ((size_t)b * NN + n) * 3;
        idx_out[ob + 0] = q0; idx_out[ob + 1] = q1; idx_out[ob + 2] = q2;
        w_out[ob + 0] = i0 / s; w_out[ob + 1] = i1 / s; w_out[ob + 2] = i2 / s;
    }
}

// ---------------- Kernel T: transpose known_feats (B,C2,M)->(B,M,C2) ----
__global__ __launch_bounds__(256) void transpose_kernel(
    const float* __restrict__ KF, float* __restrict__ KT)
{
    __shared__ float tl[32][33];
    const int b  = blockIdx.z;
    const int m0 = blockIdx.x * 32;
    const int c0 = blockIdx.y * 32;
    const int tx = threadIdx.x & 31;
    const int ty = threadIdx.x >> 5;    // 0..7
    #pragma unroll
    for (int r = 0; r < 4; ++r) {
        int c = ty + r * 8;
        tl[c][tx] = KF[((size_t)b * C2 + c0 + c) * MM + m0 + tx];
    }
    __syncthreads();
    #pragma unroll
    for (int r = 0; r < 4; ++r) {
        int m = ty + r * 8;
        KT[((size_t)b * MM + m0 + m) * C2 + c0 + tx] = tl[tx][m];
    }
}

// ---------------- Kernel B: fused gather-interp + 2-layer MFMA MLP -------
// grid 1024 (= B * N/PT), block 256 (4 waves).
__global__ __launch_bounds__(256, 3) void fp_mlp_mfma_kernel(
    const float* __restrict__ unknow_feats, // (B,C1,N)
    const float* __restrict__ KT,           // (B,M,C2)
    const short* __restrict__ W1b,          // (H1,CIN) bf16
    const float* __restrict__ b1,
    const short* __restrict__ W2b,          // (H2,H1) bf16
    const float* __restrict__ b2,
    const int*   __restrict__ idx,          // (B,N,3)
    const float* __restrict__ wgt,          // (B,N,3)
    float* __restrict__ out)                // (B,H2,N)
{
    #define XROW 392   // 384 + 8 pad (row = 784 B, 16B-multiple)
    #define HROW 264   // 256 + 8 pad (row = 528 B, 16B-multiple)
    __shared__ short Xs[PT][XROW];
    __shared__ short Hs[PT][HROW];
    __shared__ int   Is[PT * 3];
    __shared__ float Ws[PT * 3];

    const int tid  = threadIdx.x;
    const int blocks_per_b = NN / PT;             // 512
    const int b    = blockIdx.x / blocks_per_b;
    const int n0   = (blockIdx.x % blocks_per_b) * PT;
    const int w    = tid >> 6;                    // wave 0..3
    const int lane = tid & 63;
    const int lr   = lane & 15;
    const int lq   = lane >> 4;

    if (tid < PT * 3) {
        const size_t base = ((size_t)b * NN + n0) * 3;
        Is[tid] = idx[base + tid];
        Ws[tid] = wgt[base + tid];
    }
    __syncthreads();

    // ---- X-build: wave = 1 point, lane = 4 channels (coalesced float4) ----
    {
        const float* KTb = KT + (size_t)b * MM * C2;
        const int c4 = (lane << 2);               // 0..252
        #pragma unroll
        for (int pp = 0; pp < PT; pp += 4) {
            const int p = pp + w;
            const int   i0 = Is[3 * p + 0], i1 = Is[3 * p + 1], i2 = Is[3 * p + 2];
            const float w0 = Ws[3 * p + 0], w1 = Ws[3 * p + 1], w2 = Ws[3 * p + 2];
            const float4 A = *(const float4*)(KTb + (size_t)i0 * C2 + c4);
            const float4 Bv = *(const float4*)(KTb + (size_t)i1 * C2 + c4);
            const float4 Cv = *(const float4*)(KTb + (size_t)i2 * C2 + c4);
            float vx = fmaf(w0, A.x, fmaf(w1, Bv.x, w2 * Cv.x));
            float vy = fmaf(w0, A.y, fmaf(w1, Bv.y, w2 * Cv.y));
            float vz = fmaf(w0, A.z, fmaf(w1, Bv.z, w2 * Cv.z));
            float vw = fmaf(w0, A.w, fmaf(w1, Bv.w, w2 * Cv.w));
            uint2 pk;
            pk.x = pack_bf16x2(vx, vy);
            pk.y = pack_bf16x2(vz, vw);
            *(uint2*)&Xs[p][c4] = pk;             // 8B store, 2-way bank (free)
        }
        const float* UFb = unknow_feats + (size_t)b * C1 * NN + n0;
        #pragma unroll
        for (int i = 0; i < 4; ++i) {
            int e  = i * 256 + tid;
            int cc = e >> 3;                      // 0..127
            int nq = (e & 7) << 2;                // 0,4,..,28
            const float4 f = *(const float4*)(UFb + (size_t)cc * NN + nq);
            Xs[nq + 0][C2 + cc] = f32_to_bf16(f.x);
            Xs[nq + 1][C2 + cc] = f32_to_bf16(f.y);
            Xs[nq + 2][C2 + cc] = f32_to_bf16(f.z);
            Xs[nq + 3][C2 + cc] = f32_to_bf16(f.w);
        }
    }
    __syncthreads();

    // GEMM1: H[256 x PT] = ReLU(W1 * X + b1)
    {
        f32x4 acc[4][2];
        #pragma unroll
        for (int t = 0; t < 4; ++t)
            #pragma unroll
            for (int p = 0; p < 2; ++p) acc[t][p] = (f32x4){0.f, 0.f, 0.f, 0.f};

        for (int k0 = 0; k0 < CIN; k0 += 32) {
            bf16x8 a[4], x[2];
            #pragma unroll
            for (int t = 0; t < 4; ++t)
                a[t] = *(const bf16x8*)(W1b + (size_t)(w * 64 + t * 16 + lr) * CIN + k0 + lq * 8);
            #pragma unroll
            for (int p = 0; p < 2; ++p)
                x[p] = *(bf16x8*)&Xs[p * 16 + lr][k0 + lq * 8];
            #pragma unroll
            for (int t = 0; t < 4; ++t)
                #pragma unroll
                for (int p = 0; p < 2; ++p)
                    acc[t][p] = __builtin_amdgcn_mfma_f32_16x16x32_bf16(a[t], x[p], acc[t][p], 0, 0, 0);
        }
        #pragma unroll
        for (int t = 0; t < 4; ++t) {
            const int obase = w * 64 + t * 16 + lq * 4;
            float bb0 = b1[obase + 0], bb1 = b1[obase + 1],
                  bb2 = b1[obase + 2], bb3 = b1[obase + 3];
            #pragma unroll
            for (int p = 0; p < 2; ++p) {
                uint2 pk;
                pk.x = pack_bf16x2(fmaxf(acc[t][p].x + bb0, 0.f),
                                   fmaxf(acc[t][p].y + bb1, 0.f));
                pk.y = pack_bf16x2(fmaxf(acc[t][p].z + bb2, 0.f),
                                   fmaxf(acc[t][p].w + bb3, 0.f));
                *(uint2*)&Hs[p * 16 + lr][obase] = pk;
            }
        }
    }
    __syncthreads();

    // GEMM2: Out[128 x PT] = ReLU(W2 * H + b2)
    {
        f32x4 acc[2][2];
        #pragma unroll
        for (int t = 0; t < 2; ++t)
            #pragma unroll
            for (int p = 0; p < 2; ++p) acc[t][p] = (f32x4){0.f, 0.f, 0.f, 0.f};

        for (int k0 = 0; k0 < H1; k0 += 32) {
            bf16x8 a[2], h[2];
            #pragma unroll
            for (int t = 0; t < 2; ++t)
                a[t] = *(const bf16x8*)(W2b + (size_t)(w * 32 + t * 16 + lr) * H1 + k0 + lq * 8);
            #pragma unroll
            for (int p = 0; p < 2; ++p)
                h[p] = *(bf16x8*)&Hs[p * 16 + lr][k0 + lq * 8];
            #pragma unroll
            for (int t = 0; t < 2; ++t)
                #pragma unroll
                for (int p = 0; p < 2; ++p)
                    acc[t][p] = __builtin_amdgcn_mfma_f32_16x16x32_bf16(a[t], h[p], acc[t][p], 0, 0, 0);
        }
        #pragma unroll
        for (int t = 0; t < 2; ++t) {
            const int obase = w * 32 + t * 16 + lq * 4;
            #pragma unroll
            for (int p = 0; p < 2; ++p) {
                const int n = n0 + p * 16 + lr;
                #pragma unroll
                for (int r = 0; r < 4; ++r) {
                    const int o = obase + r;
                    out[((size_t)b * H2 + o) * NN + n] =
                        fmaxf(((const float*)&acc[t][p])[r] + b2[o], 0.f);
                }
            }
        }
    }
    #undef XROW
    #undef HROW
}

extern "C" void kernel_launch(void* const* d_in, const int* in_sizes, int n_in,
                              void* d_out, int out_size, void* d_ws, size_t ws_size,
                              hipStream_t stream) {
    const float* unknown      = (const float*)d_in[0];
    const float* known        = (const float*)d_in[1];
    const float* unknow_feats = (const float*)d_in[2];
    const float* known_feats  = (const float*)d_in[3];
    const float* W1           = (const float*)d_in[4];
    const float* b1           = (const float*)d_in[5];
    const float* W2           = (const float*)d_in[6];
    const float* b2           = (const float*)d_in[7];
    float* out = (float*)d_out;

    char* ws = (char*)d_ws;
    int*    idx = (int*)(ws);                      // 393216 B
    float*  wgt = (float*)(ws + 393216);           // 393216 B
    short*  W1b = (short*)(ws + 786432);           // 196608 B
    short*  W2b = (short*)(ws + 983040);           // 65536 B
    float4* kpk = (float4*)(ws + 1048576);         // 131072 B
    float*  KT  = (float*)(ws + 1179648);          // 8388608 B

    prep_kernel<<<(H1 * CIN + 255) / 256, 256, 0, stream>>>(W1, W2, known, W1b, W2b, kpk);

    dim3 gK(NN / 64, BB);
    knn3_kernel<<<gK, 512, 0, stream>>>(unknown, kpk, idx, wgt);

    dim3 gT(MM / 32, C2 / 32, BB);
    transpose_kernel<<<gT, 256, 0, stream>>>(known_feats, KT);

    fp_mlp_mfma_kernel<<<BB * (NN / PT), 256, 0, stream>>>(
        unknow_feats, KT, W1b, b1, W2b, b2, idx, wgt, out);
}

// Round 5
// 187.116 us; speedup vs baseline: 3.8565x; 1.0446x over previous
//
#include <hip/hip_runtime.h>
#include <hip/hip_bf16.h>

// PointNet2 FP: 3-NN interp + concat + MLP(384->256->128) via bf16 MFMA
#define BB 2
#define NN 16384
#define MM 4096
#define C1 128
#define C2 256
#define CIN 384
#define H1 256
#define H2 128
#define PT 32          // points per block in fused MLP kernel

typedef __attribute__((ext_vector_type(8))) short bf16x8;
typedef __attribute__((ext_vector_type(4))) float f32x4;

__device__ __forceinline__ short f32_to_bf16(float x) {
    unsigned u = __float_as_uint(x);
    u += 0x7fffu + ((u >> 16) & 1u);   // RNE
    return (short)(u >> 16);
}
__device__ __forceinline__ unsigned pack_bf16x2(float a, float b) {
    __hip_bfloat162 h = __float22bfloat162_rn(make_float2(a, b));
    union { __hip_bfloat162 h; unsigned u; } cv;
    cv.h = h;
    return cv.u;
}

// ---------------- Kernel P: prep — cast weights to bf16 + pack known ------
__global__ __launch_bounds__(256) void prep_kernel(
    const float* __restrict__ W1, const float* __restrict__ W2,
    const float* __restrict__ known,
    short* __restrict__ W1b, short* __restrict__ W2b,
    float4* __restrict__ kpk)           // (B*M) {x,y,z,|k|^2}
{
    int i = blockIdx.x * 256 + threadIdx.x;
    if (i < H1 * CIN) W1b[i] = f32_to_bf16(W1[i]);
    if (i < H2 * H1)  W2b[i] = f32_to_bf16(W2[i]);
    if (i < BB * MM) {
        float x = known[3 * i + 0], y = known[3 * i + 1], z = known[3 * i + 2];
        kpk[i] = make_float4(x, y, z, fmaf(x, x, fmaf(y, y, z * z)));
    }
}

// ---------------- Kernel A: 3-NN, two-pass (values then index recovery) ---
// block 1024 (16 waves): 64 queries (lanes, same for all waves); wave w
// scans candidates [w*256, w*256+256) via wave-uniform s_load_dwordx4.
// Pass A: values-only top-3 (fmin + 2x fmed3, 3 VALU). Merge. Pass B:
// recompute identical score, sc <= v2f match (exactly top-3 + ties) ->
// LDS slots via atomics. Final: lexicographic (sc,m) select-3 == lax.top_k
// tie rule (lower index wins).
__global__ __launch_bounds__(1024) void knn3_kernel(
    const float* __restrict__ unknown,   // (B,N,3)
    const float4* __restrict__ kpk,      // (B,M) packed
    int*   __restrict__ idx_out,         // (B,N,3)
    float* __restrict__ w_out)           // (B,N,3)
{
    __shared__ float pdv[16][64][3];   // per-wave partial top-3 values
    __shared__ float vf[64];           // per-query final v2 (3rd best)
    __shared__ float msc[64][8];       // match scores
    __shared__ int   mid[64][8];       // match indices
    __shared__ int   cnt[64];

    const int b    = blockIdx.y;
    const int tid  = threadIdx.x;
    const int lane = tid & 63;
    const int wv   = __builtin_amdgcn_readfirstlane(tid >> 6);  // uniform 0..15
    const int n    = blockIdx.x * 64 + lane;

    if (tid < 64) cnt[tid] = 0;

    const float ux = unknown[((size_t)b * NN + n) * 3 + 0];
    const float uy = unknown[((size_t)b * NN + n) * 3 + 1];
    const float uz = unknown[((size_t)b * NN + n) * 3 + 2];
    const float ax = -2.f * ux, ay = -2.f * uy, az = -2.f * uz;
    const float un = fmaf(ux, ux, fmaf(uy, uy, uz * uz));

    const int mbase = wv * 256;
    const float4* __restrict__ kp = kpk + (size_t)b * MM + mbase;

    // ---- Pass A: values-only top-3 over this wave's 256 candidates ----
    float v0 = 3e38f, v1 = 3e38f, v2 = 3e38f;
    for (int m = 0; m < 256; m += 8) {
        #pragma unroll
        for (int u = 0; u < 8; ++u) {
            const float4 k = kp[m + u];          // wave-uniform -> s_load
            float sc = fmaf(ax, k.x, fmaf(ay, k.y, fmaf(az, k.z, k.w)));
            v2 = __builtin_amdgcn_fmed3f(v1, sc, v2);
            v1 = __builtin_amdgcn_fmed3f(v0, sc, v1);
            v0 = fminf(sc, v0);
        }
    }
    pdv[wv][lane][0] = v0; pdv[wv][lane][1] = v1; pdv[wv][lane][2] = v2;
    __syncthreads();

    // ---- merge 16 partials -> final values; publish v2f ----
    if (tid < 64) {
        float r0 = 3e38f, r1 = 3e38f, r2 = 3e38f;
        #pragma unroll
        for (int ww = 0; ww < 16; ++ww) {
            #pragma unroll
            for (int k = 0; k < 3; ++k) {
                float d = pdv[ww][tid][k];
                r2 = __builtin_amdgcn_fmed3f(r1, d, r2);
                r1 = __builtin_amdgcn_fmed3f(r0, d, r1);
                r0 = fminf(d, r0);
            }
        }
        vf[tid] = r2;
    }
    __syncthreads();

    // ---- Pass B: index recovery — identical score expression ----
    const float v2f = vf[lane];
    for (int m = 0; m < 256; m += 8) {
        #pragma unroll
        for (int u = 0; u < 8; ++u) {
            const float4 k = kp[m + u];
            float sc = fmaf(ax, k.x, fmaf(ay, k.y, fmaf(az, k.z, k.w)));
            if (sc <= v2f) {                     // rare (~4.6%/wave-iter)
                int c = atomicAdd(&cnt[lane], 1);
                if (c < 8) { msc[lane][c] = sc; mid[lane][c] = mbase + m + u; }
            }
        }
    }
    __syncthreads();

    // ---- final: select 3 smallest (sc, m) lexicographic; weights ----
    if (tid < 64) {
        const int c = cnt[tid] < 8 ? cnt[tid] : 8;
        float r0 = 3e38f, r1 = 3e38f, r2 = 3e38f;
        int   q0 = 0x7FFFFFFF, q1 = 0x7FFFFFFF, q2 = 0x7FFFFFFF;
        #pragma unroll
        for (int k = 0; k < 8; ++k) {
            float d = (k < c) ? msc[tid][k] : 3e38f;
            int   j = (k < c) ? mid[tid][k] : 0x7FFFFFFF;
            const bool lt0 = (d < r0) || (d == r0 && j < q0);
            const bool lt1 = (d < r1) || (d == r1 && j < q1);
            const bool lt2 = (d < r2) || (d == r2 && j < q2);
            float nr2 = lt1 ? r1 : (lt2 ? d : r2);
            int   nq2 = lt1 ? q1 : (lt2 ? j : q2);
            float nr1 = lt0 ? r0 : (lt1 ? d : r1);
            int   nq1 = lt0 ? q0 : (lt1 ? j : q1);
            float nr0 = lt0 ? d : r0;
            int   nq0 = lt0 ? j : q0;
            r0 = nr0; r1 = nr1; r2 = nr2; q0 = nq0; q1 = nq1; q2 = nq2;
        }
        float d0 = sqrtf(fmaxf(r0 + un, 0.f));
        float d1 = sqrtf(fmaxf(r1 + un, 0.f));
        float d2 = sqrtf(fmaxf(r2 + un, 0.f));
        float i0 = 1.f / (d0 + 1e-8f);
        float i1 = 1.f / (d1 + 1e-8f);
        float i2 = 1.f / (d2 + 1e-8f);
        float s  = i0 + i1 + i2;
        const size_t ob = ((size_t)b * NN + n) * 3;
        idx_out[ob + 0] = q0; idx_out[ob + 1] = q1; idx_out[ob + 2] = q2;
        w_out[ob + 0] = i0 / s; w_out[ob + 1] = i1 / s; w_out[ob + 2] = i2 / s;
    }
}

// ---------------- Kernel T: transpose known_feats (B,C2,M)->(B,M,C2) ----
__global__ __launch_bounds__(256) void transpose_kernel(
    const float* __restrict__ KF, float* __restrict__ KT)
{
    __shared__ float tl[32][33];
    const int b  = blockIdx.z;
    const int m0 = blockIdx.x * 32;
    const int c0 = blockIdx.y * 32;
    const int tx = threadIdx.x & 31;
    const int ty = threadIdx.x >> 5;    // 0..7
    #pragma unroll
    for (int r = 0; r < 4; ++r) {
        int c = ty + r * 8;
        tl[c][tx] = KF[((size_t)b * C2 + c0 + c) * MM + m0 + tx];
    }
    __syncthreads();
    #pragma unroll
    for (int r = 0; r < 4; ++r) {
        int m = ty + r * 8;
        KT[((size_t)b * MM + m0 + m) * C2 + c0 + tx] = tl[tx][m];
    }
}

// ---------------- Kernel B: fused gather-interp + 2-layer MFMA MLP -------
// grid 1024 (= B * N/PT), block 256 (4 waves).
__global__ __launch_bounds__(256, 3) void fp_mlp_mfma_kernel(
    const float* __restrict__ unknow_feats, // (B,C1,N)
    const float* __restrict__ KT,           // (B,M,C2)
    const short* __restrict__ W1b,          // (H1,CIN) bf16
    const float* __restrict__ b1,
    const short* __restrict__ W2b,          // (H2,H1) bf16
    const float* __restrict__ b2,
    const int*   __restrict__ idx,          // (B,N,3)
    const float* __restrict__ wgt,          // (B,N,3)
    float* __restrict__ out)                // (B,H2,N)
{
    #define XROW 392   // 384 + 8 pad (row = 784 B, 16B-multiple)
    #define HROW 264   // 256 + 8 pad (row = 528 B, 16B-multiple)
    __shared__ short Xs[PT][XROW];
    __shared__ short Hs[PT][HROW];
    __shared__ int   Is[PT * 3];
    __shared__ float Ws[PT * 3];

    const int tid  = threadIdx.x;
    const int blocks_per_b = NN / PT;             // 512
    const int b    = blockIdx.x / blocks_per_b;
    const int n0   = (blockIdx.x % blocks_per_b) * PT;
    const int w    = tid >> 6;                    // wave 0..3
    const int lane = tid & 63;
    const int lr   = lane & 15;
    const int lq   = lane >> 4;

    if (tid < PT * 3) {
        const size_t base = ((size_t)b * NN + n0) * 3;
        Is[tid] = idx[base + tid];
        Ws[tid] = wgt[base + tid];
    }
    __syncthreads();

    // ---- X-build: wave = 1 point, lane = 4 channels (coalesced float4) ----
    {
        const float* KTb = KT + (size_t)b * MM * C2;
        const int c4 = (lane << 2);               // 0..252
        #pragma unroll
        for (int pp = 0; pp < PT; pp += 4) {
            const int p = pp + w;
            const int   i0 = Is[3 * p + 0], i1 = Is[3 * p + 1], i2 = Is[3 * p + 2];
            const float w0 = Ws[3 * p + 0], w1 = Ws[3 * p + 1], w2 = Ws[3 * p + 2];
            const float4 A = *(const float4*)(KTb + (size_t)i0 * C2 + c4);
            const float4 Bv = *(const float4*)(KTb + (size_t)i1 * C2 + c4);
            const float4 Cv = *(const float4*)(KTb + (size_t)i2 * C2 + c4);
            float vx = fmaf(w0, A.x, fmaf(w1, Bv.x, w2 * Cv.x));
            float vy = fmaf(w0, A.y, fmaf(w1, Bv.y, w2 * Cv.y));
            float vz = fmaf(w0, A.z, fmaf(w1, Bv.z, w2 * Cv.z));
            float vw = fmaf(w0, A.w, fmaf(w1, Bv.w, w2 * Cv.w));
            uint2 pk;
            pk.x = pack_bf16x2(vx, vy);
            pk.y = pack_bf16x2(vz, vw);
            *(uint2*)&Xs[p][c4] = pk;             // 8B store, 2-way bank (free)
        }
        const float* UFb = unknow_feats + (size_t)b * C1 * NN + n0;
        #pragma unroll
        for (int i = 0; i < 4; ++i) {
            int e  = i * 256 + tid;
            int cc = e >> 3;                      // 0..127
            int nq = (e & 7) << 2;                // 0,4,..,28
            const float4 f = *(const float4*)(UFb + (size_t)cc * NN + nq);
            Xs[nq + 0][C2 + cc] = f32_to_bf16(f.x);
            Xs[nq + 1][C2 + cc] = f32_to_bf16(f.y);
            Xs[nq + 2][C2 + cc] = f32_to_bf16(f.z);
            Xs[nq + 3][C2 + cc] = f32_to_bf16(f.w);
        }
    }
    __syncthreads();

    // GEMM1: H[256 x PT] = ReLU(W1 * X + b1)
    {
        f32x4 acc[4][2];
        #pragma unroll
        for (int t = 0; t < 4; ++t)
            #pragma unroll
            for (int p = 0; p < 2; ++p) acc[t][p] = (f32x4){0.f, 0.f, 0.f, 0.f};

        for (int k0 = 0; k0 < CIN; k0 += 32) {
            bf16x8 a[4], x[2];
            #pragma unroll
            for (int t = 0; t < 4; ++t)
                a[t] = *(const bf16x8*)(W1b + (size_t)(w * 64 + t * 16 + lr) * CIN + k0 + lq * 8);
            #pragma unroll
            for (int p = 0; p < 2; ++p)
                x[p] = *(bf16x8*)&Xs[p * 16 + lr][k0 + lq * 8];
            #pragma unroll
            for (int t = 0; t < 4; ++t)
                #pragma unroll
                for (int p = 0; p < 2; ++p)
                    acc[t][p] = __builtin_amdgcn_mfma_f32_16x16x32_bf16(a[t], x[p], acc[t][p], 0, 0, 0);
        }
        #pragma unroll
        for (int t = 0; t < 4; ++t) {
            const int obase = w * 64 + t * 16 + lq * 4;
            float bb0 = b1[obase + 0], bb1 = b1[obase + 1],
                  bb2 = b1[obase + 2], bb3 = b1[obase + 3];
            #pragma unroll
            for (int p = 0; p < 2; ++p) {
                uint2 pk;
                pk.x = pack_bf16x2(fmaxf(acc[t][p].x + bb0, 0.f),
                                   fmaxf(acc[t][p].y + bb1, 0.f));
                pk.y = pack_bf16x2(fmaxf(acc[t][p].z + bb2, 0.f),
                                   fmaxf(acc[t][p].w + bb3, 0.f));
                *(uint2*)&Hs[p * 16 + lr][obase] = pk;
            }
        }
    }
    __syncthreads();

    // GEMM2: Out[128 x PT] = ReLU(W2 * H + b2)
    {
        f32x4 acc[2][2];
        #pragma unroll
        for (int t = 0; t < 2; ++t)
            #pragma unroll
            for (int p = 0; p < 2; ++p) acc[t][p] = (f32x4){0.f, 0.f, 0.f, 0.f};

        for (int k0 = 0; k0 < H1; k0 += 32) {
            bf16x8 a[2], h[2];
            #pragma unroll
            for (int t = 0; t < 2; ++t)
                a[t] = *(const bf16x8*)(W2b + (size_t)(w * 32 + t * 16 + lr) * H1 + k0 + lq * 8);
            #pragma unroll
            for (int p = 0; p < 2; ++p)
                h[p] = *(bf16x8*)&Hs[p * 16 + lr][k0 + lq * 8];
            #pragma unroll
            for (int t = 0; t < 2; ++t)
                #pragma unroll
                for (int p = 0; p < 2; ++p)
                    acc[t][p] = __builtin_amdgcn_mfma_f32_16x16x32_bf16(a[t], h[p], acc[t][p], 0, 0, 0);
        }
        #pragma unroll
        for (int t = 0; t < 2; ++t) {
            const int obase = w * 32 + t * 16 + lq * 4;
            #pragma unroll
            for (int p = 0; p < 2; ++p) {
                const int n = n0 + p * 16 + lr;
                #pragma unroll
                for (int r = 0; r < 4; ++r) {
                    const int o = obase + r;
                    out[((size_t)b * H2 + o) * NN + n] =
                        fmaxf(((const float*)&acc[t][p])[r] + b2[o], 0.f);
                }
            }
        }
    }
    #undef XROW
    #undef HROW
}

extern "C" void kernel_launch(void* const* d_in, const int* in_sizes, int n_in,
                              void* d_out, int out_size, void* d_ws, size_t ws_size,
                              hipStream_t stream) {
    const float* unknown      = (const float*)d_in[0];
    const float* known        = (const float*)d_in[1];
    const float* unknow_feats = (const float*)d_in[2];
    const float* known_feats  = (const float*)d_in[3];
    const float* W1           = (const float*)d_in[4];
    const float* b1           = (const float*)d_in[5];
    const float* W2           = (const float*)d_in[6];
    const float* b2           = (const float*)d_in[7];
    float* out = (float*)d_out;

    char* ws = (char*)d_ws;
    int*    idx = (int*)(ws);                      // 393216 B
    float*  wgt = (float*)(ws + 393216);           // 393216 B
    short*  W1b = (short*)(ws + 786432);           // 196608 B
    short*  W2b = (short*)(ws + 983040);           // 65536 B
    float4* kpk = (float4*)(ws + 1048576);         // 131072 B
    float*  KT  = (float*)(ws + 1179648);          // 8388608 B

    prep_kernel<<<(H1 * CIN + 255) / 256, 256, 0, stream>>>(W1, W2, known, W1b, W2b, kpk);

    dim3 gK(NN / 64, BB);
    knn3_kernel<<<gK, 1024, 0, stream>>>(unknown, kpk, idx, wgt);

    dim3 gT(MM / 32, C2 / 32, BB);
    transpose_kernel<<<gT, 256, 0, stream>>>(known_feats, KT);

    fp_mlp_mfma_kernel<<<BB * (NN / PT), 256, 0, stream>>>(
        unknow_feats, KT, W1b, b1, W2b, b2, idx, wgt, out);
}

// Round 6
// 179.745 us; speedup vs baseline: 4.0146x; 1.0410x over previous
//
#include <hip/hip_runtime.h>
#include <hip/hip_bf16.h>

// PointNet2 FP: 3-NN interp + concat + MLP(384->256->128) via bf16 MFMA
#define BB 2
#define NN 16384
#define MM 4096
#define C1 128
#define C2 256
#define CIN 384
#define H1 256
#define H2 128
#define PT 32          // points per block in fused MLP kernel

typedef __attribute__((ext_vector_type(8))) short bf16x8;
typedef __attribute__((ext_vector_type(4))) float f32x4;
typedef __attribute__((ext_vector_type(2))) float f32x2;
typedef __attribute__((ext_vector_type(8))) float f32x8;

__device__ __forceinline__ short f32_to_bf16(float x) {
    unsigned u = __float_as_uint(x);
    u += 0x7fffu + ((u >> 16) & 1u);   // RNE
    return (short)(u >> 16);
}
__device__ __forceinline__ unsigned pack_bf16x2(float a, float b) {
    __hip_bfloat162 h = __float22bfloat162_rn(make_float2(a, b));
    union { __hip_bfloat162 h; unsigned u; } cv;
    cv.h = h;
    return cv.u;
}

// ------- Kernel PT2: fused transpose (2048 blocks) + prep (384 blocks) ----
// kpk layout: per 2-candidate group g: [x0,x1,y0,y1,z0,z1,n0,n1] (32 B)
__global__ __launch_bounds__(256) void prep_transpose_kernel(
    const float* __restrict__ KF, float* __restrict__ KT,
    const float* __restrict__ W1, const float* __restrict__ W2,
    const float* __restrict__ known,
    short* __restrict__ W1b, short* __restrict__ W2b,
    float* __restrict__ kpk8)
{
    const int bx = blockIdx.x;
    if (bx < 2048) {
        __shared__ float tl[32][33];
        const int b  = bx >> 10;
        const int c0 = ((bx >> 7) & 7) * 32;
        const int m0 = (bx & 127) * 32;
        const int tx = threadIdx.x & 31;
        const int ty = threadIdx.x >> 5;    // 0..7
        #pragma unroll
        for (int r = 0; r < 4; ++r) {
            int c = ty + r * 8;
            tl[c][tx] = KF[((size_t)b * C2 + c0 + c) * MM + m0 + tx];
        }
        __syncthreads();
        #pragma unroll
        for (int r = 0; r < 4; ++r) {
            int m = ty + r * 8;
            KT[((size_t)b * MM + m0 + m) * C2 + c0 + tx] = tl[tx][m];
        }
    } else {
        int i = (bx - 2048) * 256 + threadIdx.x;
        if (i < H1 * CIN) W1b[i] = f32_to_bf16(W1[i]);
        if (i < H2 * H1)  W2b[i] = f32_to_bf16(W2[i]);
        if (i < BB * MM) {
            float x = known[3 * i + 0], y = known[3 * i + 1], z = known[3 * i + 2];
            float n = fmaf(x, x, fmaf(y, y, z * z));
            int g = i >> 1, j = i & 1;
            float* base = kpk8 + (size_t)g * 8;
            base[0 + j] = x; base[2 + j] = y; base[4 + j] = z; base[6 + j] = n;
        }
    }
}

// ---------------- Kernel A: 3-NN, two-pass, packed-fp32 scores -----------
// block 1024 (16 waves): 64 queries (lanes); wave w scans candidate groups
// [w*128, w*128+128) (256 cands) via wave-uniform 32B scalar loads.
// Scores: v_pk_fma_f32 (float2). Pass A values-only; pass B index recovery
// with pair-gated compare. Lexicographic (sc,m) final == lax.top_k ties.
__global__ __launch_bounds__(1024) void knn3_kernel(
    const float* __restrict__ unknown,   // (B,N,3)
    const float* __restrict__ kpk8,      // (B*M/2) groups of 8
    int*   __restrict__ idx_out,         // (B,N,3)
    float* __restrict__ w_out)           // (B,N,3)
{
    __shared__ float pdv[16][64][3];
    __shared__ float vf[64];
    __shared__ float msc[64][8];
    __shared__ int   mid[64][8];
    __shared__ int   cnt[64];

    const int b    = blockIdx.y;
    const int tid  = threadIdx.x;
    const int lane = tid & 63;
    const int wv   = __builtin_amdgcn_readfirstlane(tid >> 6);  // uniform 0..15
    const int n    = blockIdx.x * 64 + lane;

    if (tid < 64) cnt[tid] = 0;

    const float ux = unknown[((size_t)b * NN + n) * 3 + 0];
    const float uy = unknown[((size_t)b * NN + n) * 3 + 1];
    const float uz = unknown[((size_t)b * NN + n) * 3 + 2];
    const f32x2 ax2 = {-2.f * ux, -2.f * ux};
    const f32x2 ay2 = {-2.f * uy, -2.f * uy};
    const f32x2 az2 = {-2.f * uz, -2.f * uz};
    const float un = fmaf(ux, ux, fmaf(uy, uy, uz * uz));

    const int gbase = wv * 128;                    // group index base
    const float* __restrict__ kp = kpk8 + ((size_t)b * (MM / 2) + gbase) * 8;

    // ---- Pass A: values-only top-3, 2 candidates per step ----
    float v0 = 3e38f, v1 = 3e38f, v2 = 3e38f;
    #pragma unroll 4
    for (int g = 0; g < 128; ++g) {
        const f32x8 G = *(const f32x8*)(kp + (size_t)g * 8);   // uniform 32B
        const f32x2 kx = __builtin_shufflevector(G, G, 0, 1);
        const f32x2 ky = __builtin_shufflevector(G, G, 2, 3);
        const f32x2 kz = __builtin_shufflevector(G, G, 4, 5);
        const f32x2 kn = __builtin_shufflevector(G, G, 6, 7);
        const f32x2 sc2 = __builtin_elementwise_fma(ax2, kx,
                          __builtin_elementwise_fma(ay2, ky,
                          __builtin_elementwise_fma(az2, kz, kn)));
        float sa = sc2.x;
        v2 = __builtin_amdgcn_fmed3f(v1, sa, v2);
        v1 = __builtin_amdgcn_fmed3f(v0, sa, v1);
        v0 = fminf(sa, v0);
        float sb = sc2.y;
        v2 = __builtin_amdgcn_fmed3f(v1, sb, v2);
        v1 = __builtin_amdgcn_fmed3f(v0, sb, v1);
        v0 = fminf(sb, v0);
    }
    pdv[wv][lane][0] = v0; pdv[wv][lane][1] = v1; pdv[wv][lane][2] = v2;
    __syncthreads();

    // ---- merge 16 partials -> final v2 threshold ----
    if (tid < 64) {
        float r0 = 3e38f, r1 = 3e38f, r2 = 3e38f;
        #pragma unroll
        for (int ww = 0; ww < 16; ++ww) {
            #pragma unroll
            for (int k = 0; k < 3; ++k) {
                float d = pdv[ww][tid][k];
                r2 = __builtin_amdgcn_fmed3f(r1, d, r2);
                r1 = __builtin_amdgcn_fmed3f(r0, d, r1);
                r0 = fminf(d, r0);
            }
        }
        vf[tid] = r2;
    }
    __syncthreads();

    // ---- Pass B: index recovery — identical score arithmetic ----
    const float v2f = vf[lane];
    #pragma unroll 4
    for (int g = 0; g < 128; ++g) {
        const f32x8 G = *(const f32x8*)(kp + (size_t)g * 8);
        const f32x2 kx = __builtin_shufflevector(G, G, 0, 1);
        const f32x2 ky = __builtin_shufflevector(G, G, 2, 3);
        const f32x2 kz = __builtin_shufflevector(G, G, 4, 5);
        const f32x2 kn = __builtin_shufflevector(G, G, 6, 7);
        const f32x2 sc2 = __builtin_elementwise_fma(ax2, kx,
                          __builtin_elementwise_fma(ay2, ky,
                          __builtin_elementwise_fma(az2, kz, kn)));
        if (fminf(sc2.x, sc2.y) <= v2f) {          // rare
            if (sc2.x <= v2f) {
                int c = atomicAdd(&cnt[lane], 1);
                if (c < 8) { msc[lane][c] = sc2.x; mid[lane][c] = (gbase + g) * 2; }
            }
            if (sc2.y <= v2f) {
                int c = atomicAdd(&cnt[lane], 1);
                if (c < 8) { msc[lane][c] = sc2.y; mid[lane][c] = (gbase + g) * 2 + 1; }
            }
        }
    }
    __syncthreads();

    // ---- final: 3 smallest (sc, m) lexicographic; weights ----
    if (tid < 64) {
        const int c = cnt[tid] < 8 ? cnt[tid] : 8;
        float r0 = 3e38f, r1 = 3e38f, r2 = 3e38f;
        int   q0 = 0x7FFFFFFF, q1 = 0x7FFFFFFF, q2 = 0x7FFFFFFF;
        #pragma unroll
        for (int k = 0; k < 8; ++k) {
            float d = (k < c) ? msc[tid][k] : 3e38f;
            int   j = (k < c) ? mid[tid][k] : 0x7FFFFFFF;
            const bool lt0 = (d < r0) || (d == r0 && j < q0);
            const bool lt1 = (d < r1) || (d == r1 && j < q1);
            const bool lt2 = (d < r2) || (d == r2 && j < q2);
            float nr2 = lt1 ? r1 : (lt2 ? d : r2);
            int   nq2 = lt1 ? q1 : (lt2 ? j : q2);
            float nr1 = lt0 ? r0 : (lt1 ? d : r1);
            int   nq1 = lt0 ? q0 : (lt1 ? j : q1);
            float nr0 = lt0 ? d : r0;
            int   nq0 = lt0 ? j : q0;
            r0 = nr0; r1 = nr1; r2 = nr2; q0 = nq0; q1 = nq1; q2 = nq2;
        }
        float d0 = sqrtf(fmaxf(r0 + un, 0.f));
        float d1 = sqrtf(fmaxf(r1 + un, 0.f));
        float d2 = sqrtf(fmaxf(r2 + un, 0.f));
        float i0 = 1.f / (d0 + 1e-8f);
        float i1 = 1.f / (d1 + 1e-8f);
        float i2 = 1.f / (d2 + 1e-8f);
        float s  = i0 + i1 + i2;
        const size_t ob = ((size_t)b * NN + n) * 3;
        idx_out[ob + 0] = q0; idx_out[ob + 1] = q1; idx_out[ob + 2] = q2;
        w_out[ob + 0] = i0 / s; w_out[ob + 1] = i1 / s; w_out[ob + 2] = i2 / s;
    }
}

// ---------------- Kernel B: fused gather-interp + 2-layer MFMA MLP -------
// grid 1024 (= B * N/PT), block 256 (4 waves).
__global__ __launch_bounds__(256, 3) void fp_mlp_mfma_kernel(
    const float* __restrict__ unknow_feats, // (B,C1,N)
    const float* __restrict__ KT,           // (B,M,C2)
    const short* __restrict__ W1b,          // (H1,CIN) bf16
    const float* __restrict__ b1,
    const short* __restrict__ W2b,          // (H2,H1) bf16
    const float* __restrict__ b2,
    const int*   __restrict__ idx,          // (B,N,3)
    const float* __restrict__ wgt,          // (B,N,3)
    float* __restrict__ out)                // (B,H2,N)
{
    #define XROW 392   // 384 + 8 pad (row = 784 B, 16B-multiple)
    #define HROW 264   // 256 + 8 pad (row = 528 B, 16B-multiple)
    __shared__ short Xs[PT][XROW];
    __shared__ short Hs[PT][HROW];
    __shared__ int   Is[PT * 3];
    __shared__ float Ws[PT * 3];

    const int tid  = threadIdx.x;
    const int blocks_per_b = NN / PT;             // 512
    const int b    = blockIdx.x / blocks_per_b;
    const int n0   = (blockIdx.x % blocks_per_b) * PT;
    const int w    = tid >> 6;                    // wave 0..3
    const int lane = tid & 63;
    const int lr   = lane & 15;
    const int lq   = lane >> 4;

    if (tid < PT * 3) {
        const size_t base = ((size_t)b * NN + n0) * 3;
        Is[tid] = idx[base + tid];
        Ws[tid] = wgt[base + tid];
    }
    __syncthreads();

    // ---- X-build: wave = 1 point, lane = 4 channels (coalesced float4) ----
    {
        const float* KTb = KT + (size_t)b * MM * C2;
        const int c4 = (lane << 2);               // 0..252
        #pragma unroll
        for (int pp = 0; pp < PT; pp += 4) {
            const int p = pp + w;
            const int   i0 = Is[3 * p + 0], i1 = Is[3 * p + 1], i2 = Is[3 * p + 2];
            const float w0 = Ws[3 * p + 0], w1 = Ws[3 * p + 1], w2 = Ws[3 * p + 2];
            const float4 A = *(const float4*)(KTb + (size_t)i0 * C2 + c4);
            const float4 Bv = *(const float4*)(KTb + (size_t)i1 * C2 + c4);
            const float4 Cv = *(const float4*)(KTb + (size_t)i2 * C2 + c4);
            float vx = fmaf(w0, A.x, fmaf(w1, Bv.x, w2 * Cv.x));
            float vy = fmaf(w0, A.y, fmaf(w1, Bv.y, w2 * Cv.y));
            float vz = fmaf(w0, A.z, fmaf(w1, Bv.z, w2 * Cv.z));
            float vw = fmaf(w0, A.w, fmaf(w1, Bv.w, w2 * Cv.w));
            uint2 pk;
            pk.x = pack_bf16x2(vx, vy);
            pk.y = pack_bf16x2(vz, vw);
            *(uint2*)&Xs[p][c4] = pk;             // 8B store, 2-way bank (free)
        }
        const float* UFb = unknow_feats + (size_t)b * C1 * NN + n0;
        #pragma unroll
        for (int i = 0; i < 4; ++i) {
            int e  = i * 256 + tid;
            int cc = e >> 3;                      // 0..127
            int nq = (e & 7) << 2;                // 0,4,..,28
            const float4 f = *(const float4*)(UFb + (size_t)cc * NN + nq);
            Xs[nq + 0][C2 + cc] = f32_to_bf16(f.x);
            Xs[nq + 1][C2 + cc] = f32_to_bf16(f.y);
            Xs[nq + 2][C2 + cc] = f32_to_bf16(f.z);
            Xs[nq + 3][C2 + cc] = f32_to_bf16(f.w);
        }
    }
    __syncthreads();

    // GEMM1: H[256 x PT] = ReLU(W1 * X + b1)
    {
        f32x4 acc[4][2];
        #pragma unroll
        for (int t = 0; t < 4; ++t)
            #pragma unroll
            for (int p = 0; p < 2; ++p) acc[t][p] = (f32x4){0.f, 0.f, 0.f, 0.f};

        #pragma unroll 4
        for (int k0 = 0; k0 < CIN; k0 += 32) {
            bf16x8 a[4], x[2];
            #pragma unroll
            for (int t = 0; t < 4; ++t)
                a[t] = *(const bf16x8*)(W1b + (size_t)(w * 64 + t * 16 + lr) * CIN + k0 + lq * 8);
            #pragma unroll
            for (int p = 0; p < 2; ++p)
                x[p] = *(bf16x8*)&Xs[p * 16 + lr][k0 + lq * 8];
            #pragma unroll
            for (int t = 0; t < 4; ++t)
                #pragma unroll
                for (int p = 0; p < 2; ++p)
                    acc[t][p] = __builtin_amdgcn_mfma_f32_16x16x32_bf16(a[t], x[p], acc[t][p], 0, 0, 0);
        }
        #pragma unroll
        for (int t = 0; t < 4; ++t) {
            const int obase = w * 64 + t * 16 + lq * 4;
            float bb0 = b1[obase + 0], bb1 = b1[obase + 1],
                  bb2 = b1[obase + 2], bb3 = b1[obase + 3];
            #pragma unroll
            for (int p = 0; p < 2; ++p) {
                uint2 pk;
                pk.x = pack_bf16x2(fmaxf(acc[t][p].x + bb0, 0.f),
                                   fmaxf(acc[t][p].y + bb1, 0.f));
                pk.y = pack_bf16x2(fmaxf(acc[t][p].z + bb2, 0.f),
                                   fmaxf(acc[t][p].w + bb3, 0.f));
                *(uint2*)&Hs[p * 16 + lr][obase] = pk;
            }
        }
    }
    __syncthreads();

    // GEMM2: Out[128 x PT] = ReLU(W2 * H + b2)
    {
        f32x4 acc[2][2];
        #pragma unroll
        for (int t = 0; t < 2; ++t)
            #pragma unroll
            for (int p = 0; p < 2; ++p) acc[t][p] = (f32x4){0.f, 0.f, 0.f, 0.f};

        #pragma unroll 4
        for (int k0 = 0; k0 < H1; k0 += 32) {
            bf16x8 a[2], h[2];
            #pragma unroll
            for (int t = 0; t < 2; ++t)
                a[t] = *(const bf16x8*)(W2b + (size_t)(w * 32 + t * 16 + lr) * H1 + k0 + lq * 8);
            #pragma unroll
            for (int p = 0; p < 2; ++p)
                h[p] = *(bf16x8*)&Hs[p * 16 + lr][k0 + lq * 8];
            #pragma unroll
            for (int t = 0; t < 2; ++t)
                #pragma unroll
                for (int p = 0; p < 2; ++p)
                    acc[t][p] = __builtin_amdgcn_mfma_f32_16x16x32_bf16(a[t], h[p], acc[t][p], 0, 0, 0);
        }
        #pragma unroll
        for (int t = 0; t < 2; ++t) {
            const int obase = w * 32 + t * 16 + lq * 4;
            #pragma unroll
            for (int p = 0; p < 2; ++p) {
                const int n = n0 + p * 16 + lr;
                #pragma unroll
                for (int r = 0; r < 4; ++r) {
                    const int o = obase + r;
                    out[((size_t)b * H2 + o) * NN + n] =
                        fmaxf(((const float*)&acc[t][p])[r] + b2[o], 0.f);
                }
            }
        }
    }
    #undef XROW
    #undef HROW
}

extern "C" void kernel_launch(void* const* d_in, const int* in_sizes, int n_in,
                              void* d_out, int out_size, void* d_ws, size_t ws_size,
                              hipStream_t stream) {
    const float* unknown      = (const float*)d_in[0];
    const float* known        = (const float*)d_in[1];
    const float* unknow_feats = (const float*)d_in[2];
    const float* known_feats  = (const float*)d_in[3];
    const float* W1           = (const float*)d_in[4];
    const float* b1           = (const float*)d_in[5];
    const float* W2           = (const float*)d_in[6];
    const float* b2           = (const float*)d_in[7];
    float* out = (float*)d_out;

    char* ws = (char*)d_ws;
    int*    idx  = (int*)(ws);                      // 393216 B
    float*  wgt  = (float*)(ws + 393216);           // 393216 B
    short*  W1b  = (short*)(ws + 786432);           // 196608 B
    short*  W2b  = (short*)(ws + 983040);           // 65536 B
    float*  kpk8 = (float*)(ws + 1048576);          // 131072 B
    float*  KT   = (float*)(ws + 1179648);          // 8388608 B

    prep_transpose_kernel<<<2048 + 384, 256, 0, stream>>>(
        known_feats, KT, W1, W2, known, W1b, W2b, kpk8);

    dim3 gK(NN / 64, BB);
    knn3_kernel<<<gK, 1024, 0, stream>>>(unknown, kpk8, idx, wgt);

    fp_mlp_mfma_kernel<<<BB * (NN / PT), 256, 0, stream>>>(
        unknow_feats, KT, W1b, b1, W2b, b2, idx, wgt, out);
}

// Round 7
// 166.242 us; speedup vs baseline: 4.3407x; 1.0812x over previous
//
#include <hip/hip_runtime.h>
#include <hip/hip_bf16.h>

// PointNet2 FP: 3-NN interp + concat + MLP(384->256->128) via bf16 MFMA
#define BB 2
#define NN 16384
#define MM 4096
#define C1 128
#define C2 256
#define CIN 384
#define H1 256
#define H2 128
#define PT 32          // points per block in fused MLP kernel
#define XROW 392       // 384 + 8 pad (row = 784 B)

typedef __attribute__((ext_vector_type(8))) short bf16x8;
typedef __attribute__((ext_vector_type(4))) float f32x4;
typedef __attribute__((ext_vector_type(2))) float f32x2;
typedef __attribute__((ext_vector_type(8))) float f32x8;

__device__ __forceinline__ short f32_to_bf16(float x) {
    unsigned u = __float_as_uint(x);
    u += 0x7fffu + ((u >> 16) & 1u);   // RNE
    return (short)(u >> 16);
}
__device__ __forceinline__ float bf16_to_f32(unsigned short u) {
    union { unsigned u; float f; } c; c.u = ((unsigned)u) << 16; return c.f;
}
__device__ __forceinline__ unsigned pack_bf16x2(float a, float b) {
    __hip_bfloat162 h = __float22bfloat162_rn(make_float2(a, b));
    union { __hip_bfloat162 h; unsigned u; } cv;
    cv.h = h;
    return cv.u;
}

// ---------------- Kernel 1: pack known -> kpk8 (tiny) ----------------
// kpk layout per 2-candidate group g: [x0,x1,y0,y1,z0,z1,n0,n1] (32 B)
__global__ __launch_bounds__(1024) void kpk_prep_kernel(
    const float* __restrict__ known, float* __restrict__ kpk8)
{
    int i = blockIdx.x * 1024 + threadIdx.x;
    if (i < BB * MM) {
        float x = known[3 * i + 0], y = known[3 * i + 1], z = known[3 * i + 2];
        float n = fmaf(x, x, fmaf(y, y, z * z));
        int g = i >> 1, j = i & 1;
        float* base = kpk8 + (size_t)g * 8;
        base[0 + j] = x; base[2 + j] = y; base[4 + j] = z; base[6 + j] = n;
    }
}

// ------- Kernel 2: fused 3-NN (blocks 0..511) + transpose->bf16
//         (512..2559) + weight casts (2560..2655). Block = 1024 threads.
__global__ __launch_bounds__(1024) void knn_aux_kernel(
    const float* __restrict__ unknown,   // (B,N,3)
    const float* __restrict__ kpk8,      // packed groups
    int*   __restrict__ idx_out,         // (B,N,3)
    float* __restrict__ w_out,           // (B,N,3)
    const float* __restrict__ KF,        // (B,C2,M)
    unsigned short* __restrict__ KT16,   // (B,M,C2) bf16
    const float* __restrict__ W1, const float* __restrict__ W2,
    short* __restrict__ W1b, short* __restrict__ W2b)
{
    __shared__ float pdv[16][64][3];
    __shared__ float vf[64];
    __shared__ float msc[64][8];
    __shared__ int   mid[64][8];
    __shared__ int   cnt[64];
    __shared__ float tl[32][33];

    const int bx  = blockIdx.x;
    const int tid = threadIdx.x;

    if (bx < 512) {
        // ================= 3-NN: two-pass, packed-fp32 scores ============
        const int lane = tid & 63;
        const int wv   = __builtin_amdgcn_readfirstlane(tid >> 6);  // 0..15
        const int b    = bx >> 8;
        const int n    = (bx & 255) * 64 + lane;

        if (tid < 64) cnt[tid] = 0;

        const float ux = unknown[((size_t)b * NN + n) * 3 + 0];
        const float uy = unknown[((size_t)b * NN + n) * 3 + 1];
        const float uz = unknown[((size_t)b * NN + n) * 3 + 2];
        const f32x2 ax2 = {-2.f * ux, -2.f * ux};
        const f32x2 ay2 = {-2.f * uy, -2.f * uy};
        const f32x2 az2 = {-2.f * uz, -2.f * uz};
        const float un = fmaf(ux, ux, fmaf(uy, uy, uz * uz));

        const int gbase = wv * 128;
        const float* __restrict__ kp = kpk8 + ((size_t)b * (MM / 2) + gbase) * 8;

        float v0 = 3e38f, v1 = 3e38f, v2 = 3e38f;
        #pragma unroll 4
        for (int g = 0; g < 128; ++g) {
            const f32x8 G = *(const f32x8*)(kp + (size_t)g * 8);   // uniform
            const f32x2 kx = __builtin_shufflevector(G, G, 0, 1);
            const f32x2 ky = __builtin_shufflevector(G, G, 2, 3);
            const f32x2 kz = __builtin_shufflevector(G, G, 4, 5);
            const f32x2 kn = __builtin_shufflevector(G, G, 6, 7);
            const f32x2 sc2 = __builtin_elementwise_fma(ax2, kx,
                              __builtin_elementwise_fma(ay2, ky,
                              __builtin_elementwise_fma(az2, kz, kn)));
            float sa = sc2.x;
            v2 = __builtin_amdgcn_fmed3f(v1, sa, v2);
            v1 = __builtin_amdgcn_fmed3f(v0, sa, v1);
            v0 = fminf(sa, v0);
            float sb = sc2.y;
            v2 = __builtin_amdgcn_fmed3f(v1, sb, v2);
            v1 = __builtin_amdgcn_fmed3f(v0, sb, v1);
            v0 = fminf(sb, v0);
        }
        pdv[wv][lane][0] = v0; pdv[wv][lane][1] = v1; pdv[wv][lane][2] = v2;
        __syncthreads();

        if (tid < 64) {
            float r0 = 3e38f, r1 = 3e38f, r2 = 3e38f;
            #pragma unroll
            for (int ww = 0; ww < 16; ++ww) {
                #pragma unroll
                for (int k = 0; k < 3; ++k) {
                    float d = pdv[ww][tid][k];
                    r2 = __builtin_amdgcn_fmed3f(r1, d, r2);
                    r1 = __builtin_amdgcn_fmed3f(r0, d, r1);
                    r0 = fminf(d, r0);
                }
            }
            vf[tid] = r2;
        }
        __syncthreads();

        const float v2f = vf[lane];
        #pragma unroll 4
        for (int g = 0; g < 128; ++g) {
            const f32x8 G = *(const f32x8*)(kp + (size_t)g * 8);
            const f32x2 kx = __builtin_shufflevector(G, G, 0, 1);
            const f32x2 ky = __builtin_shufflevector(G, G, 2, 3);
            const f32x2 kz = __builtin_shufflevector(G, G, 4, 5);
            const f32x2 kn = __builtin_shufflevector(G, G, 6, 7);
            const f32x2 sc2 = __builtin_elementwise_fma(ax2, kx,
                              __builtin_elementwise_fma(ay2, ky,
                              __builtin_elementwise_fma(az2, kz, kn)));
            if (fminf(sc2.x, sc2.y) <= v2f) {
                if (sc2.x <= v2f) {
                    int c = atomicAdd(&cnt[lane], 1);
                    if (c < 8) { msc[lane][c] = sc2.x; mid[lane][c] = (gbase + g) * 2; }
                }
                if (sc2.y <= v2f) {
                    int c = atomicAdd(&cnt[lane], 1);
                    if (c < 8) { msc[lane][c] = sc2.y; mid[lane][c] = (gbase + g) * 2 + 1; }
                }
            }
        }
        __syncthreads();

        if (tid < 64) {
            const int c = cnt[tid] < 8 ? cnt[tid] : 8;
            float r0 = 3e38f, r1 = 3e38f, r2 = 3e38f;
            int   q0 = 0x7FFFFFFF, q1 = 0x7FFFFFFF, q2 = 0x7FFFFFFF;
            #pragma unroll
            for (int k = 0; k < 8; ++k) {
                float d = (k < c) ? msc[tid][k] : 3e38f;
                int   j = (k < c) ? mid[tid][k] : 0x7FFFFFFF;
                const bool lt0 = (d < r0) || (d == r0 && j < q0);
                const bool lt1 = (d < r1) || (d == r1 && j < q1);
                const bool lt2 = (d < r2) || (d == r2 && j < q2);
                float nr2 = lt1 ? r1 : (lt2 ? d : r2);
                int   nq2 = lt1 ? q1 : (lt2 ? j : q2);
                float nr1 = lt0 ? r0 : (lt1 ? d : r1);
                int   nq1 = lt0 ? q0 : (lt1 ? j : q1);
                float nr0 = lt0 ? d : r0;
                int   nq0 = lt0 ? j : q0;
                r0 = nr0; r1 = nr1; r2 = nr2; q0 = nq0; q1 = nq1; q2 = nq2;
            }
            float d0 = sqrtf(fmaxf(r0 + un, 0.f));
            float d1 = sqrtf(fmaxf(r1 + un, 0.f));
            float d2 = sqrtf(fmaxf(r2 + un, 0.f));
            float i0 = 1.f / (d0 + 1e-8f);
            float i1 = 1.f / (d1 + 1e-8f);
            float i2 = 1.f / (d2 + 1e-8f);
            float s  = i0 + i1 + i2;
            const size_t ob = ((size_t)(bx >> 8) * NN + n) * 3;
            idx_out[ob + 0] = q0; idx_out[ob + 1] = q1; idx_out[ob + 2] = q2;
            w_out[ob + 0] = i0 / s; w_out[ob + 1] = i1 / s; w_out[ob + 2] = i2 / s;
        }
    } else if (bx < 2560) {
        // ================= transpose KF (B,C2,M) -> KT16 (B,M,C2) bf16 ===
        const int t  = bx - 512;
        const int b  = t >> 10;
        const int c0 = ((t >> 7) & 7) * 32;
        const int m0 = (t & 127) * 32;
        if (tid < 1024) {
            const int tx = tid & 31;
            const int ty = tid >> 5;            // 0..31
            tl[ty][tx] = KF[((size_t)b * C2 + c0 + ty) * MM + m0 + tx];
            __syncthreads();
            KT16[((size_t)b * MM + m0 + ty) * C2 + c0 + tx] = (unsigned short)f32_to_bf16(tl[tx][ty]);
        }
    } else {
        // ================= weight casts ==================================
        int i = (bx - 2560) * 1024 + tid;
        if (i < H1 * CIN) W1b[i] = f32_to_bf16(W1[i]);
        if (i < H2 * H1)  W2b[i] = f32_to_bf16(W2[i]);
    }
}

// ---------------- Kernel 3: fused gather-interp + 2-layer MFMA MLP -------
// grid 1024 (= B * N/PT), block 256 (4 waves). Single aliased LDS buffer
// XH holds X (phase 1) then H (phase 2); GEMM1 acc carried in registers
// across the barrier. LDS ~25.9 KB -> 4 blocks/CU resident (16 waves/CU).
__global__ __launch_bounds__(256, 4) void fp_mlp_mfma_kernel(
    const float* __restrict__ unknow_feats,   // (B,C1,N)
    const unsigned short* __restrict__ KT16,  // (B,M,C2) bf16
    const short* __restrict__ W1b,            // (H1,CIN) bf16
    const float* __restrict__ b1,
    const short* __restrict__ W2b,            // (H2,H1) bf16
    const float* __restrict__ b2,
    const int*   __restrict__ idx,            // (B,N,3)
    const float* __restrict__ wgt,            // (B,N,3)
    float* __restrict__ out)                  // (B,H2,N)
{
    __shared__ short XH[PT][XROW];
    __shared__ int   Is[PT * 3];
    __shared__ float Ws[PT * 3];

    const int tid  = threadIdx.x;
    const int blocks_per_b = NN / PT;             // 512
    const int b    = blockIdx.x / blocks_per_b;
    const int n0   = (blockIdx.x % blocks_per_b) * PT;
    const int w    = tid >> 6;                    // wave 0..3
    const int lane = tid & 63;
    const int lr   = lane & 15;
    const int lq   = lane >> 4;

    if (tid < PT * 3) {
        const size_t base = ((size_t)b * NN + n0) * 3;
        Is[tid] = idx[base + tid];
        Ws[tid] = wgt[base + tid];
    }
    __syncthreads();

    // ---- X-build: wave = 1 point, lane = 4 channels; issue all 24 gathers
    {
        const unsigned short* KTb = KT16 + (size_t)b * MM * C2;
        const int c4 = (lane << 2);               // 0..252
        ushort4 g[8][3];
        #pragma unroll
        for (int i = 0; i < 8; ++i) {
            const int p = i * 4 + w;
            g[i][0] = *(const ushort4*)(KTb + (size_t)Is[3 * p + 0] * C2 + c4);
            g[i][1] = *(const ushort4*)(KTb + (size_t)Is[3 * p + 1] * C2 + c4);
            g[i][2] = *(const ushort4*)(KTb + (size_t)Is[3 * p + 2] * C2 + c4);
        }
        #pragma unroll
        for (int i = 0; i < 8; ++i) {
            const int p = i * 4 + w;
            const float w0 = Ws[3 * p + 0], w1 = Ws[3 * p + 1], w2 = Ws[3 * p + 2];
            float vx = fmaf(w0, bf16_to_f32(g[i][0].x), fmaf(w1, bf16_to_f32(g[i][1].x), w2 * bf16_to_f32(g[i][2].x)));
            float vy = fmaf(w0, bf16_to_f32(g[i][0].y), fmaf(w1, bf16_to_f32(g[i][1].y), w2 * bf16_to_f32(g[i][2].y)));
            float vz = fmaf(w0, bf16_to_f32(g[i][0].z), fmaf(w1, bf16_to_f32(g[i][1].z), w2 * bf16_to_f32(g[i][2].z)));
            float vw = fmaf(w0, bf16_to_f32(g[i][0].w), fmaf(w1, bf16_to_f32(g[i][1].w), w2 * bf16_to_f32(g[i][2].w)));
            uint2 pk;
            pk.x = pack_bf16x2(vx, vy);
            pk.y = pack_bf16x2(vz, vw);
            *(uint2*)&XH[p][c4] = pk;
        }
        const float* UFb = unknow_feats + (size_t)b * C1 * NN + n0;
        #pragma unroll
        for (int i = 0; i < 4; ++i) {
            int e  = i * 256 + tid;
            int cc = e >> 3;                      // 0..127
            int nq = (e & 7) << 2;                // 0,4,..,28
            const float4 f = *(const float4*)(UFb + (size_t)cc * NN + nq);
            XH[nq + 0][C2 + cc] = f32_to_bf16(f.x);
            XH[nq + 1][C2 + cc] = f32_to_bf16(f.y);
            XH[nq + 2][C2 + cc] = f32_to_bf16(f.z);
            XH[nq + 3][C2 + cc] = f32_to_bf16(f.w);
        }
    }
    __syncthreads();

    // GEMM1: acc = W1 * X  (acc stays in registers across the alias barrier)
    f32x4 acc[4][2];
    #pragma unroll
    for (int t = 0; t < 4; ++t)
        #pragma unroll
        for (int p = 0; p < 2; ++p) acc[t][p] = (f32x4){0.f, 0.f, 0.f, 0.f};

    #pragma unroll 4
    for (int k0 = 0; k0 < CIN; k0 += 32) {
        bf16x8 a[4], x[2];
        #pragma unroll
        for (int t = 0; t < 4; ++t)
            a[t] = *(const bf16x8*)(W1b + (size_t)(w * 64 + t * 16 + lr) * CIN + k0 + lq * 8);
        #pragma unroll
        for (int p = 0; p < 2; ++p)
            x[p] = *(bf16x8*)&XH[p * 16 + lr][k0 + lq * 8];
        #pragma unroll
        for (int t = 0; t < 4; ++t)
            #pragma unroll
            for (int p = 0; p < 2; ++p)
                acc[t][p] = __builtin_amdgcn_mfma_f32_16x16x32_bf16(a[t], x[p], acc[t][p], 0, 0, 0);
    }
    __syncthreads();   // all X reads done — safe to overwrite XH with H

    // H = ReLU(acc + b1) -> XH (cols 0..255)
    #pragma unroll
    for (int t = 0; t < 4; ++t) {
        const int obase = w * 64 + t * 16 + lq * 4;
        float bb0 = b1[obase + 0], bb1 = b1[obase + 1],
              bb2 = b1[obase + 2], bb3 = b1[obase + 3];
        #pragma unroll
        for (int p = 0; p < 2; ++p) {
            uint2 pk;
            pk.x = pack_bf16x2(fmaxf(acc[t][p].x + bb0, 0.f),
                               fmaxf(acc[t][p].y + bb1, 0.f));
            pk.y = pack_bf16x2(fmaxf(acc[t][p].z + bb2, 0.f),
                               fmaxf(acc[t][p].w + bb3, 0.f));
            *(uint2*)&XH[p * 16 + lr][obase] = pk;
        }
    }
    __syncthreads();

    // GEMM2: Out[128 x PT] = ReLU(W2 * H + b2)
    {
        f32x4 acc2[2][2];
        #pragma unroll
        for (int t = 0; t < 2; ++t)
            #pragma unroll
            for (int p = 0; p < 2; ++p) acc2[t][p] = (f32x4){0.f, 0.f, 0.f, 0.f};

        #pragma unroll 4
        for (int k0 = 0; k0 < H1; k0 += 32) {
            bf16x8 a[2], h[2];
            #pragma unroll
            for (int t = 0; t < 2; ++t)
                a[t] = *(const bf16x8*)(W2b + (size_t)(w * 32 + t * 16 + lr) * H1 + k0 + lq * 8);
            #pragma unroll
            for (int p = 0; p < 2; ++p)
                h[p] = *(bf16x8*)&XH[p * 16 + lr][k0 + lq * 8];
            #pragma unroll
            for (int t = 0; t < 2; ++t)
                #pragma unroll
                for (int p = 0; p < 2; ++p)
                    acc2[t][p] = __builtin_amdgcn_mfma_f32_16x16x32_bf16(a[t], h[p], acc2[t][p], 0, 0, 0);
        }
        #pragma unroll
        for (int t = 0; t < 2; ++t) {
            const int obase = w * 32 + t * 16 + lq * 4;
            #pragma unroll
            for (int p = 0; p < 2; ++p) {
                const int n = n0 + p * 16 + lr;
                #pragma unroll
                for (int r = 0; r < 4; ++r) {
                    const int o = obase + r;
                    out[((size_t)b * H2 + o) * NN + n] =
                        fmaxf(((const float*)&acc2[t][p])[r] + b2[o], 0.f);
                }
            }
        }
    }
}

extern "C" void kernel_launch(void* const* d_in, const int* in_sizes, int n_in,
                              void* d_out, int out_size, void* d_ws, size_t ws_size,
                              hipStream_t stream) {
    const float* unknown      = (const float*)d_in[0];
    const float* known        = (const float*)d_in[1];
    const float* unknow_feats = (const float*)d_in[2];
    const float* known_feats  = (const float*)d_in[3];
    const float* W1           = (const float*)d_in[4];
    const float* b1           = (const float*)d_in[5];
    const float* W2           = (const float*)d_in[6];
    const float* b2           = (const float*)d_in[7];
    float* out = (float*)d_out;

    char* ws = (char*)d_ws;
    int*            idx  = (int*)(ws);                      // 393216 B
    float*          wgt  = (float*)(ws + 393216);           // 393216 B
    short*          W1b  = (short*)(ws + 786432);           // 196608 B
    short*          W2b  = (short*)(ws + 983040);           // 65536 B
    float*          kpk8 = (float*)(ws + 1048576);          // 131072 B
    unsigned short* KT16 = (unsigned short*)(ws + 1179648); // 4194304 B

    kpk_prep_kernel<<<8, 1024, 0, stream>>>(known, kpk8);

    knn_aux_kernel<<<2656, 1024, 0, stream>>>(
        unknown, kpk8, idx, wgt, known_feats, KT16, W1, W2, W1b, W2b);

    fp_mlp_mfma_kernel<<<BB * (NN / PT), 256, 0, stream>>>(
        unknow_feats, KT16, W1b, b1, W2b, b2, idx, wgt, out);
}